// Round 9
// baseline (372.741 us; speedup 1.0000x reference)
//
#include <hip/hip_runtime.h>
#include <hip/hip_bf16.h>
#include <math.h>

// ---------- types ----------
typedef __attribute__((ext_vector_type(8))) short   short8;
typedef __attribute__((ext_vector_type(4))) short   short4v;
typedef __attribute__((ext_vector_type(8))) __bf16  bf16x8;
typedef __attribute__((ext_vector_type(4))) float   f32x4;

typedef const __attribute__((address_space(1))) void cgv_t;
typedef __attribute__((address_space(3))) void lv_t;

__device__ __forceinline__ float bs2f(short s) {
  unsigned int u = ((unsigned int)(unsigned short)s) << 16;
  return __builtin_bit_cast(float, u);
}
__device__ __forceinline__ short f2bs(float f) {
  __hip_bfloat16 h = __float2bfloat16(f);  // RNE
  return __builtin_bit_cast(short, h);
}
// async global->LDS, 16B per lane; lds base must be wave-uniform
__device__ __forceinline__ void glds16(const short* g, short* l) {
  __builtin_amdgcn_global_load_lds((cgv_t*)g, (lv_t*)l, 16, 0, 0);
}

// B=4, S=1024, D=1024, H=8, FF=4096, DK=128. I/O f32; internals bf16.
// Head-sum trick: attn[s,g] = sum_k P[s,k] * V8[k,g], V8 = xn @ Wv8,
// Wv8[:,r] = sum_{e<8} Wv[:,8r+e]. Attention fused flash-style.
// Q is pre-scaled by (1/sqrt(128))*log2(e) at the QKV epilogue, so the
// flash softmax runs entirely in the exp2 domain (raw v_exp_f32).
// Reference's raw reshape: (b,h,s,gg) attn value lands at x1 flat index
// ((b*8+h)*1024+s)*128+gg (verified round 6/8).

// ---------- device bodies for the fused prep kernel ----------
// weight transpose + f32->bf16: out[C][R] = bf16(in[R][C]); 64x64 tile
__device__ __forceinline__ void tr_body(const float* __restrict__ in,
                                        short* __restrict__ out,
                                        int R, int C, int bx, int by,
                                        short* T) {
  const int r0 = by * 64, c0 = bx * 64;
  const int t = threadIdx.x;
  {
    const int rr = t >> 4;           // 0..15
    const int cc = (t & 15) << 2;    // 0..60 step 4
#pragma unroll
    for (int h = 0; h < 4; h++) {
      const int row = rr + h * 16;
      f32x4 v = *(const f32x4*)(in + (long)(r0 + row) * C + c0 + cc);
#pragma unroll
      for (int e = 0; e < 4; e++) T[row * 72 + cc + e] = f2bs(v[e]);
    }
  }
  __syncthreads();
  {
    const int cr = t >> 3;           // 0..31
    const int rs = (t & 7) << 3;     // 0..56 step 8
#pragma unroll
    for (int h = 0; h < 2; h++) {
      const int c = cr + h * 32;
      short8 v;
#pragma unroll
      for (int e = 0; e < 8; e++) v[e] = T[(rs + e) * 72 + c];
      *(short8*)(out + (long)(c0 + c) * R + r0 + rs) = v;
    }
  }
}

// wv8T[r][k] = bf16( sum_{e<8} Wv[k][8r+e] ); 64x64 tile
__device__ __forceinline__ void wv8_body(const float* __restrict__ Wv,
                                         short* __restrict__ out,
                                         int bx, int by, short* T) {
  const int r0 = bx * 64, k0 = by * 64;
  const int t = threadIdx.x;
  const int wave = t >> 6, lane = t & 63;
  const int r = r0 + lane;
#pragma unroll 4
  for (int i = 0; i < 16; i++) {
    const int k = k0 + wave * 16 + i;
    const float* src = Wv + (long)k * 8192 + 8 * r;
    f32x4 a = *(const f32x4*)src;
    f32x4 b = *(const f32x4*)(src + 4);
    float s = (a[0] + a[1] + a[2] + a[3]) + (b[0] + b[1] + b[2] + b[3]);
    T[lane * 72 + wave * 16 + i] = f2bs(s);
  }
  __syncthreads();
  const int rr = t >> 3, kc = (t & 7) << 3;
#pragma unroll
  for (int half = 0; half < 2; half++) {
    const int rl = rr + half * 32;
    *(short8*)(out + (long)(r0 + rl) * 1024 + k0 + kc) = *(const short8*)&T[rl * 72 + kc];
  }
}

// layernorm row of 1024; f32 in/params; bf16 out
__device__ __forceinline__ void ln_body(const float* __restrict__ in,
                                        const float* __restrict__ g,
                                        const float* __restrict__ b,
                                        short* __restrict__ out, int row,
                                        float* rs, float* rq) {
  const int t = threadIdx.x;
  const long base = (long)row * 1024 + t * 4;
  f32x4 f = *(const f32x4*)(in + base);
  float v[4] = {f[0], f[1], f[2], f[3]};
  float s1 = v[0] + v[1] + v[2] + v[3];
  float s2 = v[0]*v[0] + v[1]*v[1] + v[2]*v[2] + v[3]*v[3];
#pragma unroll
  for (int off = 32; off; off >>= 1) {
    s1 += __shfl_xor(s1, off);
    s2 += __shfl_xor(s2, off);
  }
  if ((t & 63) == 0) { rs[t >> 6] = s1; rq[t >> 6] = s2; }
  __syncthreads();
  s1 = rs[0] + rs[1] + rs[2] + rs[3];
  s2 = rq[0] + rq[1] + rq[2] + rq[3];
  const float mean = s1 * (1.0f / 1024.0f);
  const float var  = s2 * (1.0f / 1024.0f) - mean * mean;
  const float rstd = rsqrtf(var + 1e-5f);
  f32x4 gv = *(const f32x4*)(g + t * 4);
  f32x4 bv = *(const f32x4*)(b + t * 4);
  short4v o;
#pragma unroll
  for (int i = 0; i < 4; i++)
    o[i] = f2bs((v[i] - mean) * rstd * gv[i] + bv[i]);
  *(short4v*)(out + base) = o;
}

// ---------- fused prep: LN1 + all weight transposes + wv8 + biases ----------
// block ranges: [0,4096) ln1 | +256 trWq | +256 trWk | +256 wv8 |
// +1024 trW1 | +1024 trW2 | +4 bv8 | +2 copy bq/bk. Total 6918.
__global__ __launch_bounds__(256) void prep_k(
    const float* __restrict__ x, const float* __restrict__ g1,
    const float* __restrict__ b1, short* __restrict__ xn,
    const float* __restrict__ Wq, short* __restrict__ wqT,
    const float* __restrict__ Wk, short* __restrict__ wkT,
    const float* __restrict__ Wv, short* __restrict__ wv8T,
    const float* __restrict__ W1, short* __restrict__ w1T,
    const float* __restrict__ W2, short* __restrict__ w2T,
    const float* __restrict__ bq, const float* __restrict__ bk,
    const float* __restrict__ bv, float* __restrict__ bQKV) {
  __shared__ __align__(16) short T[64 * 72];
  __shared__ float rs[4], rq[4];
  const int t = threadIdx.x;
  int bid = blockIdx.x;
  if (bid < 4096) { ln_body(x, g1, b1, xn, bid, rs, rq); return; }
  bid -= 4096;
  if (bid < 256) { tr_body(Wq, wqT, 1024, 1024, bid & 15, bid >> 4, T); return; }
  bid -= 256;
  if (bid < 256) { tr_body(Wk, wkT, 1024, 1024, bid & 15, bid >> 4, T); return; }
  bid -= 256;
  if (bid < 256) { wv8_body(Wv, wv8T, bid & 15, bid >> 4, T); return; }
  bid -= 256;
  if (bid < 1024) { tr_body(W1, w1T, 1024, 4096, bid & 63, bid >> 6, T); return; }
  bid -= 1024;
  if (bid < 1024) { tr_body(W2, w2T, 4096, 1024, bid & 15, bid >> 4, T); return; }
  bid -= 1024;
  if (bid < 4) {
    const int r = bid * 256 + t;
    f32x4 a = *(const f32x4*)(bv + 8 * r);
    f32x4 b = *(const f32x4*)(bv + 8 * r + 4);
    bQKV[2048 + r] = (a[0] + a[1] + a[2] + a[3]) + (b[0] + b[1] + b[2] + b[3]);
    return;
  }
  bid -= 4;
  if (bid == 0) { *(f32x4*)(bQKV + t * 4) = *(const f32x4*)(bq + t * 4); }
  else          { *(f32x4*)(bQKV + 1024 + t * 4) = *(const f32x4*)(bk + t * 4); }
}

// ---------- layernorm kernel (2nd LN: x1 -> xn2) ----------
__global__ __launch_bounds__(256) void ln_k(const float* __restrict__ in,
                                            const float* __restrict__ g,
                                            const float* __restrict__ b,
                                            short* __restrict__ out) {
  __shared__ float rs[4], rq[4];
  ln_body(in, g, b, out, blockIdx.x, rs, rq);
}

// ---------- split-K=4 reduce: d_out = p0..p3 (x1+bias folded into p0) ----------
__global__ __launch_bounds__(256) void reduce4_k(const float* __restrict__ p,
                                                 float* __restrict__ out) {
  const int t = threadIdx.x;
  const long base = (long)blockIdx.x * 1024 + t * 4;
  f32x4 a = *(const f32x4*)(p + base);
  f32x4 b = *(const f32x4*)(p + 4194304 + base);
  f32x4 c = *(const f32x4*)(p + 8388608 + base);
  f32x4 d = *(const f32x4*)(p + 12582912 + base);
  *(f32x4*)(out + base) = a + b + c + d;
}

// ---------- fused flash attention (+head-sum + residual) ----------
// Q pre-scaled by SC*log2e; softmax in exp2 domain; defer-max (THR=8,
// exact: m cancels in o/l). XCD swizzle: XCD r owns bh in [4r,4r+4) so
// its K/V working set (2MB) is L2-resident. T2 XOR swizzle on LDS slabs.
__global__ __launch_bounds__(256, 2) void flash_k(
    const short* __restrict__ Qg_, const short* __restrict__ Kg_,
    const short* __restrict__ V8T, const float* __restrict__ xg,
    float* __restrict__ x1) {
  __shared__ __align__(16) short smem[40960];  // 80 KB exactly
  short* Qs = smem;            // 4 * [64][32]  (slab 2048 shorts)
  short* Ks = smem + 8192;     // 4 * [128][32] (slab 4096); P reuses rows 0..63
  short* Vs = smem + 24576;    // 4 * [128][32]

  const int t = threadIdx.x;
  const int wave = t >> 6, lane = t & 63;
  const int llo = lane & 15, lhi = lane >> 4;

  // XCD-grouped remap: 512 blocks, XCD r <- bh in [4r, 4r+4), all 16 q-tiles
  int lin = blockIdx.x + (blockIdx.y << 4);
  lin = (lin & 7) * 64 + (lin >> 3);
  const int q0 = (lin & 15) * 64;
  const int bh = lin >> 4, b = bh >> 3, h = bh & 7;

  const short* Qg = Qg_ + ((long)(b * 1024 + q0)) * 1024 + h * 128;
  const short* Kg = Kg_ + ((long)b * 1024) * 1024 + h * 128;
  const short* Vg = V8T + (long)bh * 131072;   // [128 g][1024 s]

  const int srow = t >> 2;
  const int sgc = (((t & 3) ^ ((t >> 3) & 3)) << 3);  // pre-swizzled src chunk
  const int wbase = wave * 512;          // wave-uniform stage base (shorts)
  const int swzo = ((lhi ^ ((llo >> 1) & 3)) << 3);   // swizzled frag chunk
  const int arow = (wave * 16 + llo) * 32 + swzo;     // Q / P frag read

#pragma unroll
  for (int kk = 0; kk < 4; kk++)
    glds16(Qg + (long)srow * 1024 + kk * 32 + sgc, Qs + kk * 2048 + wbase);

  f32x4 o[8];
  float mR[4], lR[4];
#pragma unroll
  for (int i = 0; i < 8; i++) o[i] = f32x4{0.f, 0.f, 0.f, 0.f};
#pragma unroll
  for (int r = 0; r < 4; r++) { mR[r] = -1e30f; lR[r] = 0.f; }

  for (int it = 0; it < 8; it++) {
    const int kt0 = it * 128;
#pragma unroll
    for (int kk = 0; kk < 4; kk++) {
      glds16(Kg + (long)(kt0 + srow) * 1024 + kk * 32 + sgc,
             Ks + kk * 4096 + wbase);
      glds16(Kg + (long)(kt0 + 64 + srow) * 1024 + kk * 32 + sgc,
             Ks + kk * 4096 + 2048 + wbase);
      glds16(Vg + (long)srow * 1024 + kt0 + kk * 32 + sgc,
             Vs + kk * 4096 + wbase);
      glds16(Vg + (long)(64 + srow) * 1024 + kt0 + kk * 32 + sgc,
             Vs + kk * 4096 + 2048 + wbase);
    }
    __syncthreads();

    f32x4 s[8];
#pragma unroll
    for (int i = 0; i < 8; i++) s[i] = f32x4{0.f, 0.f, 0.f, 0.f};
#pragma unroll
    for (int kk = 0; kk < 4; kk++) {
      bf16x8 aq = *(const bf16x8*)(Qs + kk * 2048 + arow);
#pragma unroll
      for (int ct = 0; ct < 8; ct++) {
        bf16x8 bk = *(const bf16x8*)(Ks + kk * 4096 + (ct * 16 + llo) * 32 + swzo);
        s[ct] = __builtin_amdgcn_mfma_f32_16x16x32_bf16(aq, bk, s[ct], 0, 0, 0);
      }
    }
    // scores already scaled by SC*log2e (folded into Q); exp2 domain
    float mt[4];
#pragma unroll
    for (int r = 0; r < 4; r++) {
      float m = s[0][r];
#pragma unroll
      for (int ct = 1; ct < 8; ct++) m = fmaxf(m, s[ct][r]);
      m = fmaxf(m, __shfl_xor(m, 1));
      m = fmaxf(m, __shfl_xor(m, 2));
      m = fmaxf(m, __shfl_xor(m, 4));
      m = fmaxf(m, __shfl_xor(m, 8));
      mt[r] = m;
    }
    // defer-max: only rescale when max grew by > 8 (P bounded by 2^8)
    bool need = (mt[0] > mR[0] + 8.f) | (mt[1] > mR[1] + 8.f) |
                (mt[2] > mR[2] + 8.f) | (mt[3] > mR[3] + 8.f);
    if (__any(need)) {
      float alpha[4];
#pragma unroll
      for (int r = 0; r < 4; r++) {
        const float mn = fmaxf(mR[r], mt[r]);
        alpha[r] = __builtin_amdgcn_exp2f(mR[r] - mn);
        mR[r] = mn;
        lR[r] *= alpha[r];
      }
#pragma unroll
      for (int ct = 0; ct < 8; ct++)
#pragma unroll
        for (int r = 0; r < 4; r++) o[ct][r] *= alpha[r];
    }
#pragma unroll
    for (int ct = 0; ct < 8; ct++)
#pragma unroll
      for (int r = 0; r < 4; r++)
        s[ct][r] = __builtin_amdgcn_exp2f(s[ct][r] - mR[r]);
#pragma unroll
    for (int r = 0; r < 4; r++) {
      float ls = s[0][r];
#pragma unroll
      for (int ct = 1; ct < 8; ct++) ls += s[ct][r];
      ls += __shfl_xor(ls, 1);
      ls += __shfl_xor(ls, 2);
      ls += __shfl_xor(ls, 4);
      ls += __shfl_xor(ls, 8);
      lR[r] += ls;
    }
    __syncthreads();

    // P -> Ks rows 0..63, swizzled slots (col' matches swizzled P-read)
#pragma unroll
    for (int ct = 0; ct < 8; ct++) {
      const int chunk = ((ct & 1) << 1) | (llo >> 3);
      const int cl = llo & 7;
#pragma unroll
      for (int r = 0; r < 4; r++) {
        const int row = wave * 16 + lhi * 4 + r;
        const int xr = ((lhi << 1) | (r >> 1)) & 3;
        Ks[(ct >> 1) * 4096 + row * 32 + (((chunk ^ xr) << 3) | cl)] = f2bs(s[ct][r]);
      }
    }
    __syncthreads();

#pragma unroll
    for (int kk = 0; kk < 4; kk++) {
      bf16x8 ap = *(const bf16x8*)(Ks + kk * 4096 + arow);
#pragma unroll
      for (int ct = 0; ct < 8; ct++) {
        bf16x8 bv = *(const bf16x8*)(Vs + kk * 4096 + (ct * 16 + llo) * 32 + swzo);
        o[ct] = __builtin_amdgcn_mfma_f32_16x16x32_bf16(ap, bv, o[ct], 0, 0, 0);
      }
    }
    __syncthreads();
  }

  float inv[4];
#pragma unroll
  for (int r = 0; r < 4; r++) inv[r] = 1.0f / lR[r];
#pragma unroll
  for (int ct = 0; ct < 8; ct++) {
#pragma unroll
    for (int r = 0; r < 4; r++) {
      const int row = q0 + wave * 16 + lhi * 4 + r;
      const long idx = ((long)(b * 8 + h) * 1024 + row) * 128 + ct * 16 + llo;
      x1[idx] = xg[idx] + o[ct][r] * inv[r];
    }
  }
}

// ======================================================================
// 256x256 8-phase bf16 GEMM (T1 XCD swizzle + T2 swizzle + T3/T4 counted
// vmcnt + T5 setprio). 512 thr = 8 waves (2M x 4N), per-wave out 128x64,
// BK=64 (2 K-halves). LDS 128 KiB STATIC. One trailing barrier per phase.
// Epilogues: E_GELU (bias+GELU->bf16), E_QKV (bias->bf16; z==0 scaled by
// SC*log2e; z==2 -> transposed write into V8T head layout via aux),
// E_PART (f32 partial; z==0 also adds x1(aux) + bias for the FFN2 fold).
// Per-z offsets: A += z*azk, Bt += z*bzk (shorts), bias += z*biasl.
// Requires NT=K/64 even, >=4; grid blocks %8 == 0.
// ======================================================================
enum { E_GELU = 0, E_QKV = 1, E_PART = 2 };

#define MF16(va, vb, vc) __builtin_amdgcn_mfma_f32_16x16x32_bf16(va, vb, vc, 0, 0, 0)
#define VMW(n) asm volatile("s_waitcnt vmcnt(" #n ")" ::: "memory")
#define NOPS ((void)0)

#define STAGE_A(BUF, KH, KB) do {                                          \
    glds16(Ag + (KB), smem + ((BUF) * 2 + (KH)) * 8192 + wofs);            \
    glds16(Ag2 + (KB), smem + ((BUF) * 2 + (KH)) * 8192 + 4096 + wofs);    \
  } while (0)
#define STAGE_B(BUF, KH, KB) do {                                          \
    glds16(Bg + (KB), smem + 32768 + ((BUF) * 2 + (KH)) * 8192 + wofs);    \
    glds16(Bg2 + (KB), smem + 32768 + ((BUF) * 2 + (KH)) * 8192 + 4096 + wofs); \
  } while (0)

// LOADB=1 -> load vb0..vb3 (B frags) this phase; LOADB=0 -> reuse.
#define PHASE(RH, KH, BUF, LOADB, STAGE_STMT, WAIT_STMT)                   \
  {                                                                        \
    const short* Ar_ = smem + ((BUF) * 2 + (KH)) * 8192 + aoff + (RH) * 2048; \
    bf16x8 a0 = *(const bf16x8*)(Ar_);                                     \
    bf16x8 a1 = *(const bf16x8*)(Ar_ + 512);                               \
    bf16x8 a2 = *(const bf16x8*)(Ar_ + 1024);                              \
    bf16x8 a3 = *(const bf16x8*)(Ar_ + 1536);                              \
    if (LOADB) {                                                           \
      const short* Br_ = smem + 32768 + ((BUF) * 2 + (KH)) * 8192 + boff;  \
      vb0 = *(const bf16x8*)(Br_);                                         \
      vb1 = *(const bf16x8*)(Br_ + 512);                                   \
      vb2 = *(const bf16x8*)(Br_ + 1024);                                  \
      vb3 = *(const bf16x8*)(Br_ + 1536);                                  \
    }                                                                      \
    STAGE_STMT;                                                            \
    __builtin_amdgcn_s_setprio(1);                                         \
    acc[(RH) * 4 + 0][0] = MF16(a0, vb0, acc[(RH) * 4 + 0][0]);            \
    acc[(RH) * 4 + 0][1] = MF16(a0, vb1, acc[(RH) * 4 + 0][1]);            \
    acc[(RH) * 4 + 0][2] = MF16(a0, vb2, acc[(RH) * 4 + 0][2]);            \
    acc[(RH) * 4 + 0][3] = MF16(a0, vb3, acc[(RH) * 4 + 0][3]);            \
    acc[(RH) * 4 + 1][0] = MF16(a1, vb0, acc[(RH) * 4 + 1][0]);            \
    acc[(RH) * 4 + 1][1] = MF16(a1, vb1, acc[(RH) * 4 + 1][1]);            \
    acc[(RH) * 4 + 1][2] = MF16(a1, vb2, acc[(RH) * 4 + 1][2]);            \
    acc[(RH) * 4 + 1][3] = MF16(a1, vb3, acc[(RH) * 4 + 1][3]);            \
    acc[(RH) * 4 + 2][0] = MF16(a2, vb0, acc[(RH) * 4 + 2][0]);            \
    acc[(RH) * 4 + 2][1] = MF16(a2, vb1, acc[(RH) * 4 + 2][1]);            \
    acc[(RH) * 4 + 2][2] = MF16(a2, vb2, acc[(RH) * 4 + 2][2]);            \
    acc[(RH) * 4 + 2][3] = MF16(a2, vb3, acc[(RH) * 4 + 2][3]);            \
    acc[(RH) * 4 + 3][0] = MF16(a3, vb0, acc[(RH) * 4 + 3][0]);            \
    acc[(RH) * 4 + 3][1] = MF16(a3, vb1, acc[(RH) * 4 + 3][1]);            \
    acc[(RH) * 4 + 3][2] = MF16(a3, vb2, acc[(RH) * 4 + 3][2]);            \
    acc[(RH) * 4 + 3][3] = MF16(a3, vb3, acc[(RH) * 4 + 3][3]);            \
    __builtin_amdgcn_s_setprio(0);                                         \
    WAIT_STMT;                                                             \
    __builtin_amdgcn_sched_barrier(0);                                     \
    __builtin_amdgcn_s_barrier();                                          \
    __builtin_amdgcn_sched_barrier(0);                                     \
  }

#define TILE8(T, BUF)                                                        \
  PHASE(0, 0, BUF, 1, STAGE_A(1 - (BUF), 1, ((T) + 1) * 64 + 32), NOPS);     \
  PHASE(1, 0, BUF, 0, STAGE_B(1 - (BUF), 1, ((T) + 1) * 64 + 32), VMW(8));   \
  PHASE(0, 1, BUF, 1, STAGE_A(BUF, 0, ((T) + 2) * 64), NOPS);                \
  PHASE(1, 1, BUF, 0, STAGE_B(BUF, 0, ((T) + 2) * 64), VMW(8))

template <int EPI>
__global__ __launch_bounds__(512, 2) void gemm256(
    const short* __restrict__ A, int lda, long azk,
    const short* __restrict__ Bt, int ldb, long bzk,
    const float* __restrict__ bias, long biasl,
    void* __restrict__ outp, long czl, int ldc,
    void* __restrict__ aux, int K) {
  __shared__ __align__(16) short smem[65536];  // 128 KiB static

  const int t = threadIdx.x;
  const int wave = t >> 6, lane = t & 63;
  const int llo = lane & 15, lhi = lane >> 4;
  const int wm = wave >> 2, wn = wave & 3;

  // XCD-chunked bijective remap: keep x-partners (shared A panel) on one XCD
  int lin = blockIdx.x + gridDim.x * (blockIdx.y + gridDim.y * blockIdx.z);
  const int nwg = gridDim.x * gridDim.y * gridDim.z;  // % 8 == 0
  lin = (lin & 7) * (nwg >> 3) + (lin >> 3);
  const int bx = lin % gridDim.x;
  const int rem = lin / gridDim.x;
  const int by = rem % gridDim.y;
  const int z = rem / gridDim.y;

  const int bm0 = by * 256, bn0 = bx * 256;
  A += (long)z * azk;
  Bt += (long)z * bzk;

  // staging constants: thread loads rows (srow, srow+128), chunk pre-swizzled
  const int srow = t >> 2;                                 // 0..127
  const int sgc = (((t & 3) ^ ((t >> 3) & 3)) << 3);       // source chunk (shorts)
  const short* Ag  = A  + (long)(bm0 + srow) * lda + sgc;
  const short* Ag2 = A  + (long)(bm0 + 128 + srow) * lda + sgc;
  const short* Bg  = Bt + (long)(bn0 + srow) * ldb + sgc;
  const short* Bg2 = Bt + (long)(bn0 + 128 + srow) * ldb + sgc;
  const int wofs = wave * 512;                             // wave-uniform LDS base

  // fragment read constants (rows within region are multiples of 16 + llo)
  const int swz = ((lhi ^ ((llo >> 1) & 3)) << 3);
  const int aoff = (wm * 128 + llo) * 32 + swz;            // + RH*2048 + rt*512
  const int boff = (wn * 64 + llo) * 32 + swz;             // + ct*512

  f32x4 acc[8][4];
#pragma unroll
  for (int i = 0; i < 8; i++)
#pragma unroll
    for (int j = 0; j < 4; j++) acc[i][j] = f32x4{0.f, 0.f, 0.f, 0.f};
  bf16x8 vb0, vb1, vb2, vb3;  // B frags, loaded at RH=0, reused at RH=1

  const int NT = K >> 6;  // even, >= 4

  // prologue: tile0 (both K-halves) + tile1 K-half0; keep newest 8 in flight
  STAGE_A(0, 0, 0);  STAGE_B(0, 0, 0);
  STAGE_A(0, 1, 32); STAGE_B(0, 1, 32);
  STAGE_A(1, 0, 64); STAGE_B(1, 0, 64);
  VMW(8);
  __builtin_amdgcn_sched_barrier(0);
  __builtin_amdgcn_s_barrier();
  __builtin_amdgcn_sched_barrier(0);

  for (int tt = 0; tt < NT - 2; tt += 2) {
    TILE8(tt, 0);
    TILE8(tt + 1, 1);
  }
  // tail tile NT-2 (buf 0): stage only tile NT-1's K-half1
  PHASE(0, 0, 0, 1, STAGE_A(1, 1, (NT - 1) * 64 + 32), NOPS);
  PHASE(1, 0, 0, 0, STAGE_B(1, 1, (NT - 1) * 64 + 32), VMW(8));
  PHASE(0, 1, 0, 1, NOPS, NOPS);
  PHASE(1, 1, 0, 0, NOPS, VMW(4));
  // tail tile NT-1 (buf 1): no staging
  PHASE(0, 0, 1, 1, NOPS, NOPS);
  PHASE(1, 0, 1, 0, NOPS, VMW(0));
  PHASE(0, 1, 1, 1, NOPS, NOPS);
  PHASE(1, 1, 1, 0, NOPS, NOPS);

  if (EPI == E_PART) {
    // f32 partial, direct stores; z==0 folds in x1 + bias (FFN2 residual)
    float* P = (float*)outp + (long)z * czl;
    const float* x1p = (const float*)aux;
    const bool add0 = (z == 0);
#pragma unroll
    for (int ct = 0; ct < 4; ct++) {
      const int col = bn0 + wn * 64 + ct * 16 + llo;
      const float bval = add0 ? bias[col] : 0.f;
#pragma unroll
      for (int rt = 0; rt < 8; rt++) {
#pragma unroll
        for (int r = 0; r < 4; r++) {
          const int row = bm0 + wm * 128 + rt * 16 + lhi * 4 + r;
          float v = acc[rt][ct][r];
          if (add0) v += x1p[(long)row * 1024 + col] + bval;
          P[(long)row * ldc + col] = v;
        }
      }
    }
  } else if (EPI == E_QKV && z == 2) {
    // V8 projection: transposed write into V8T[bh][g][s] via per-wave slab
    short* slab = smem + wave * 4352;   // [64 cols][68] shorts
    const int bb = bm0 >> 10, sbase = (bm0 & 1023) + wm * 128;
    float bv4[4];
#pragma unroll
    for (int ct = 0; ct < 4; ct++)
      bv4[ct] = bias[z * biasl + bn0 + wn * 64 + ct * 16 + llo];
    const int gcol = bn0 + wn * 64 + lane;
    short* dst0 = (short*)aux + ((long)(bb * 8 + (gcol >> 7))) * 131072 +
                  (long)(gcol & 127) * 1024 + sbase;
#pragma unroll
    for (int p = 0; p < 2; p++) {
#pragma unroll
      for (int rt4 = 0; rt4 < 4; rt4++) {
#pragma unroll
        for (int ct = 0; ct < 4; ct++) {
#pragma unroll
          for (int r = 0; r < 4; r++) {
            float v = acc[p * 4 + rt4][ct][r] + bv4[ct];
            slab[(ct * 16 + llo) * 68 + rt4 * 16 + lhi * 4 + r] = f2bs(v);
          }
        }
      }
#pragma unroll
      for (int j = 0; j < 8; j++)
        *(short8*)(dst0 + p * 64 + j * 8) = *(const short8*)&slab[lane * 68 + j * 8];
    }
  } else {
    // bias (+GELU/+Qscale) -> bf16 via per-wave LDS slab -> short8 stores
    short* C = (short*)outp + (long)z * czl;
    short* slab = smem + wave * 4864;   // [64 rows][76 cols] shorts
    float bv4[4];
#pragma unroll
    for (int ct = 0; ct < 4; ct++)
      bv4[ct] = bias[z * biasl + bn0 + wn * 64 + ct * 16 + llo];
    const int rl0 = lane >> 3, cb8 = (lane & 7) << 3;
    const short* srd = slab + rl0 * 76 + cb8;
    short* Cw = C + (long)(bm0 + wm * 128 + rl0) * ldc + bn0 + wn * 64 + cb8;
#pragma unroll
    for (int p = 0; p < 2; p++) {
#pragma unroll
      for (int rt4 = 0; rt4 < 4; rt4++) {
#pragma unroll
        for (int ct = 0; ct < 4; ct++) {
#pragma unroll
          for (int r = 0; r < 4; r++) {
            float v = acc[p * 4 + rt4][ct][r] + bv4[ct];
            if (EPI == E_GELU)
              v = 0.5f * v * (1.0f + erff(v * 0.70710678118654752f));
            if (EPI == E_QKV && z == 0)
              v *= 0.12751744476582f;  // (1/sqrt(128)) * log2(e)
            slab[(rt4 * 16 + lhi * 4 + r) * 76 + ct * 16 + llo] = f2bs(v);
          }
        }
      }
#pragma unroll
      for (int j = 0; j < 8; j++) {
        short8 v = *(const short8*)(srd + j * 8 * 76);
        *(short8*)(Cw + ((long)p * 64 + j * 8) * ldc) = v;
      }
    }
  }
}

// ---------- launch ----------
extern "C" void kernel_launch(void* const* d_in, const int* in_sizes, int n_in,
                              void* d_out, int out_size, void* d_ws, size_t ws_size,
                              hipStream_t stream) {
  const float* x   = (const float*)d_in[0];
  // d_in[1] = mask (int32) — unused in infer path
  const float* g1  = (const float*)d_in[2];
  const float* b1  = (const float*)d_in[3];
  const float* Wq  = (const float*)d_in[4];
  const float* bq  = (const float*)d_in[5];
  const float* Wk  = (const float*)d_in[6];
  const float* bk  = (const float*)d_in[7];
  const float* Wv  = (const float*)d_in[8];
  const float* bv  = (const float*)d_in[9];
  const float* g2  = (const float*)d_in[10];
  const float* b2  = (const float*)d_in[11];
  const float* W1  = (const float*)d_in[12];
  const float* bw1 = (const float*)d_in[13];
  const float* W2  = (const float*)d_in[14];
  const float* bw2 = (const float*)d_in[15];

  char* ws = (char*)d_ws;
  const long MB = 1024 * 1024;
  // layout (peak 137MB; ws >= 189MB proven in round 5):
  float* bQKV  = (float*)(ws);            // [3][1024] f32: bq | bk | bv8
  float* x1    = (float*)(ws + 1 * MB);   // [4096,1024] f32  [1,17)
  short* wqT   = (short*)(ws + 17 * MB);  // [17,19)
  short* wkT   = (short*)(ws + 19 * MB);  // [19,21)  contiguous with wqT
  short* wv8T  = (short*)(ws + 21 * MB);  // [21,23)  contiguous (z*2MB)
  short* xn    = (short*)(ws + 23 * MB);  // [23,31)
  short* Q     = (short*)(ws + 31 * MB);  // [31,39)
  short* Kb    = (short*)(ws + 39 * MB);  // [39,47)  contiguous with Q
  short* V8T   = (short*)(ws + 47 * MB);  // [32][128][1024] bf16 [47,55)
  // FFN overlay (attention scratch dead by then):
  short* xn2  = (short*)(ws + 17 * MB);  // [17,25)
  short* Hb   = (short*)(ws + 25 * MB);  // [25,57)
  short* w1T  = (short*)(ws + 57 * MB);  // [57,65)
  short* w2T  = (short*)(ws + 65 * MB);  // [65,73)
  float* part = (float*)(ws + 73 * MB);  // [4][4096,1024] f32 [73,137)

  // fused prep: LN1 + Wq/Wk/W1/W2 transposes + wv8 + bv8 + bias copies
  prep_k<<<6918, 256, 0, stream>>>(x, g1, b1, xn,
                                   Wq, wqT, Wk, wkT, Wv, wv8T,
                                   W1, w1T, W2, w2T,
                                   bq, bk, bv, bQKV);

  // QKV: z=0 -> Q (pre-scaled), z=1 -> Kb, z=2 -> V8T (transposed). K=1024.
  gemm256<E_QKV><<<dim3(4, 16, 3), 512, 0, stream>>>(
      xn, 1024, 0, wqT, 1024, 1048576, bQKV, 1024,
      Q, 4194304, 1024, V8T, 1024);

  // fused attention: scores+softmax+PV8+head-sum+residual -> x1
  flash_k<<<dim3(16, 32), 256, 0, stream>>>(Q, Kb, V8T, x, x1);

  // ---- FFN phase ----
  ln_k<<<4096, 256, 0, stream>>>(x1, g2, b2, xn2);

  // FFN1 + exact GELU -> Hb (bf16). K=1024.
  gemm256<E_GELU><<<dim3(16, 16, 1), 512, 0, stream>>>(
      xn2, 1024, 0, w1T, 1024, 0, bw1, 0,
      Hb, 0, 4096, nullptr, 1024);

  // FFN2 split-K=4: f32 partials; z==0 adds x1 + bw2 (residual fold).
  gemm256<E_PART><<<dim3(4, 16, 4), 512, 0, stream>>>(
      Hb, 4096, 1024, w2T, 4096, 1024, bw2, 0,
      part, 4194304, 1024, x1, 1024);

  reduce4_k<<<4096, 256, 0, stream>>>(part, (float*)d_out);
}

// Round 10
// 353.477 us; speedup vs baseline: 1.0545x; 1.0545x over previous
//
#include <hip/hip_runtime.h>
#include <hip/hip_bf16.h>
#include <math.h>

// ---------- types ----------
typedef __attribute__((ext_vector_type(8))) short   short8;
typedef __attribute__((ext_vector_type(4))) short   short4v;
typedef __attribute__((ext_vector_type(8))) __bf16  bf16x8;
typedef __attribute__((ext_vector_type(4))) float   f32x4;

typedef const __attribute__((address_space(1))) void cgv_t;
typedef __attribute__((address_space(3))) void lv_t;

__device__ __forceinline__ float bs2f(short s) {
  unsigned int u = ((unsigned int)(unsigned short)s) << 16;
  return __builtin_bit_cast(float, u);
}
__device__ __forceinline__ short f2bs(float f) {
  __hip_bfloat16 h = __float2bfloat16(f);  // RNE
  return __builtin_bit_cast(short, h);
}
// async global->LDS, 16B per lane; lds base must be wave-uniform
__device__ __forceinline__ void glds16(const short* g, short* l) {
  __builtin_amdgcn_global_load_lds((cgv_t*)g, (lv_t*)l, 16, 0, 0);
}

// B=4, S=1024, D=1024, H=8, FF=4096, DK=128. I/O f32; internals bf16.
// Head-sum trick: attn[s,g] = sum_k P[s,k] * V8[k,g], V8 = xn @ Wv8,
// Wv8[:,r] = sum_{e<8} Wv[:,8r+e]. Attention fused flash-style.
// Q is pre-scaled by (1/sqrt(128))*log2(e) at the QKV epilogue, so the
// flash softmax runs entirely in the exp2 domain (raw v_exp_f32).
// Reference's raw reshape: (b,h,s,gg) attn value lands at x1 flat index
// ((b*8+h)*1024+s)*128+gg (verified round 6/8).

// ---------- device bodies for the fused prep kernel ----------
// weight transpose + f32->bf16: out[C][R] = bf16(in[R][C]); 64x64 tile
__device__ __forceinline__ void tr_body(const float* __restrict__ in,
                                        short* __restrict__ out,
                                        int R, int C, int bx, int by,
                                        short* T) {
  const int r0 = by * 64, c0 = bx * 64;
  const int t = threadIdx.x;
  {
    const int rr = t >> 4;           // 0..15
    const int cc = (t & 15) << 2;    // 0..60 step 4
#pragma unroll
    for (int h = 0; h < 4; h++) {
      const int row = rr + h * 16;
      f32x4 v = *(const f32x4*)(in + (long)(r0 + row) * C + c0 + cc);
#pragma unroll
      for (int e = 0; e < 4; e++) T[row * 72 + cc + e] = f2bs(v[e]);
    }
  }
  __syncthreads();
  {
    const int cr = t >> 3;           // 0..31
    const int rs = (t & 7) << 3;     // 0..56 step 8
#pragma unroll
    for (int h = 0; h < 2; h++) {
      const int c = cr + h * 32;
      short8 v;
#pragma unroll
      for (int e = 0; e < 8; e++) v[e] = T[(rs + e) * 72 + c];
      *(short8*)(out + (long)(c0 + c) * R + r0 + rs) = v;
    }
  }
}

// wv8T[r][k] = bf16( sum_{e<8} Wv[k][8r+e] ); 64x64 tile
__device__ __forceinline__ void wv8_body(const float* __restrict__ Wv,
                                         short* __restrict__ out,
                                         int bx, int by, short* T) {
  const int r0 = bx * 64, k0 = by * 64;
  const int t = threadIdx.x;
  const int wave = t >> 6, lane = t & 63;
  const int r = r0 + lane;
#pragma unroll 4
  for (int i = 0; i < 16; i++) {
    const int k = k0 + wave * 16 + i;
    const float* src = Wv + (long)k * 8192 + 8 * r;
    f32x4 a = *(const f32x4*)src;
    f32x4 b = *(const f32x4*)(src + 4);
    float s = (a[0] + a[1] + a[2] + a[3]) + (b[0] + b[1] + b[2] + b[3]);
    T[lane * 72 + wave * 16 + i] = f2bs(s);
  }
  __syncthreads();
  const int rr = t >> 3, kc = (t & 7) << 3;
#pragma unroll
  for (int half = 0; half < 2; half++) {
    const int rl = rr + half * 32;
    *(short8*)(out + (long)(r0 + rl) * 1024 + k0 + kc) = *(const short8*)&T[rl * 72 + kc];
  }
}

// layernorm row of 1024; f32 in/params; bf16 out
__device__ __forceinline__ void ln_body(const float* __restrict__ in,
                                        const float* __restrict__ g,
                                        const float* __restrict__ b,
                                        short* __restrict__ out, int row,
                                        float* rs, float* rq) {
  const int t = threadIdx.x;
  const long base = (long)row * 1024 + t * 4;
  f32x4 f = *(const f32x4*)(in + base);
  float v[4] = {f[0], f[1], f[2], f[3]};
  float s1 = v[0] + v[1] + v[2] + v[3];
  float s2 = v[0]*v[0] + v[1]*v[1] + v[2]*v[2] + v[3]*v[3];
#pragma unroll
  for (int off = 32; off; off >>= 1) {
    s1 += __shfl_xor(s1, off);
    s2 += __shfl_xor(s2, off);
  }
  if ((t & 63) == 0) { rs[t >> 6] = s1; rq[t >> 6] = s2; }
  __syncthreads();
  s1 = rs[0] + rs[1] + rs[2] + rs[3];
  s2 = rq[0] + rq[1] + rq[2] + rq[3];
  const float mean = s1 * (1.0f / 1024.0f);
  const float var  = s2 * (1.0f / 1024.0f) - mean * mean;
  const float rstd = rsqrtf(var + 1e-5f);
  f32x4 gv = *(const f32x4*)(g + t * 4);
  f32x4 bv = *(const f32x4*)(b + t * 4);
  short4v o;
#pragma unroll
  for (int i = 0; i < 4; i++)
    o[i] = f2bs((v[i] - mean) * rstd * gv[i] + bv[i]);
  *(short4v*)(out + base) = o;
}

// ---------- fused prep: LN1 + all weight transposes + wv8 + biases ----------
// block ranges: [0,4096) ln1 | +256 trWq | +256 trWk | +256 wv8 |
// +1024 trW1 | +1024 trW2 | +4 bv8 | +2 copy bq/bk. Total 6918.
__global__ __launch_bounds__(256) void prep_k(
    const float* __restrict__ x, const float* __restrict__ g1,
    const float* __restrict__ b1, short* __restrict__ xn,
    const float* __restrict__ Wq, short* __restrict__ wqT,
    const float* __restrict__ Wk, short* __restrict__ wkT,
    const float* __restrict__ Wv, short* __restrict__ wv8T,
    const float* __restrict__ W1, short* __restrict__ w1T,
    const float* __restrict__ W2, short* __restrict__ w2T,
    const float* __restrict__ bq, const float* __restrict__ bk,
    const float* __restrict__ bv, float* __restrict__ bQKV) {
  __shared__ __align__(16) short T[64 * 72];
  __shared__ float rs[4], rq[4];
  const int t = threadIdx.x;
  int bid = blockIdx.x;
  if (bid < 4096) { ln_body(x, g1, b1, xn, bid, rs, rq); return; }
  bid -= 4096;
  if (bid < 256) { tr_body(Wq, wqT, 1024, 1024, bid & 15, bid >> 4, T); return; }
  bid -= 256;
  if (bid < 256) { tr_body(Wk, wkT, 1024, 1024, bid & 15, bid >> 4, T); return; }
  bid -= 256;
  if (bid < 256) { wv8_body(Wv, wv8T, bid & 15, bid >> 4, T); return; }
  bid -= 256;
  if (bid < 1024) { tr_body(W1, w1T, 1024, 4096, bid & 63, bid >> 6, T); return; }
  bid -= 1024;
  if (bid < 1024) { tr_body(W2, w2T, 4096, 1024, bid & 15, bid >> 4, T); return; }
  bid -= 1024;
  if (bid < 4) {
    const int r = bid * 256 + t;
    f32x4 a = *(const f32x4*)(bv + 8 * r);
    f32x4 b = *(const f32x4*)(bv + 8 * r + 4);
    bQKV[2048 + r] = (a[0] + a[1] + a[2] + a[3]) + (b[0] + b[1] + b[2] + b[3]);
    return;
  }
  bid -= 4;
  if (bid == 0) { *(f32x4*)(bQKV + t * 4) = *(const f32x4*)(bq + t * 4); }
  else          { *(f32x4*)(bQKV + 1024 + t * 4) = *(const f32x4*)(bk + t * 4); }
}

// ---------- layernorm kernel (2nd LN: x1 -> xn2) ----------
__global__ __launch_bounds__(256) void ln_k(const float* __restrict__ in,
                                            const float* __restrict__ g,
                                            const float* __restrict__ b,
                                            short* __restrict__ out) {
  __shared__ float rs[4], rq[4];
  ln_body(in, g, b, out, blockIdx.x, rs, rq);
}

// ---------- split-K=4 reduce: d_out = p0..p3 + x1 + bias ----------
__global__ __launch_bounds__(256) void reduce4_k(const float* __restrict__ p,
                                                 const float* __restrict__ x1,
                                                 const float* __restrict__ bias,
                                                 float* __restrict__ out) {
  const int t = threadIdx.x;
  const long base = (long)blockIdx.x * 1024 + t * 4;
  f32x4 a = *(const f32x4*)(p + base);
  f32x4 b = *(const f32x4*)(p + 4194304 + base);
  f32x4 c = *(const f32x4*)(p + 8388608 + base);
  f32x4 d = *(const f32x4*)(p + 12582912 + base);
  f32x4 e = *(const f32x4*)(x1 + base);
  f32x4 g = *(const f32x4*)(bias + t * 4);
  *(f32x4*)(out + base) = a + b + c + d + e + g;
}

// ---------- fused flash attention (+head-sum + residual) ----------
// Q pre-scaled by SC*log2e; softmax in exp2 domain; defer-max (THR=8,
// exact: m cancels in o/l). XCD swizzle: XCD r owns bh in [4r,4r+4) so
// its K/V working set (2MB) is L2-resident. T2 XOR swizzle on LDS slabs.
__global__ __launch_bounds__(256, 2) void flash_k(
    const short* __restrict__ Qg_, const short* __restrict__ Kg_,
    const short* __restrict__ V8T, const float* __restrict__ xg,
    float* __restrict__ x1) {
  __shared__ __align__(16) short smem[40960];  // 80 KB exactly
  short* Qs = smem;            // 4 * [64][32]  (slab 2048 shorts)
  short* Ks = smem + 8192;     // 4 * [128][32] (slab 4096); P reuses rows 0..63
  short* Vs = smem + 24576;    // 4 * [128][32]

  const int t = threadIdx.x;
  const int wave = t >> 6, lane = t & 63;
  const int llo = lane & 15, lhi = lane >> 4;

  // XCD-grouped remap: 512 blocks, XCD r <- bh in [4r, 4r+4), all 16 q-tiles
  int lin = blockIdx.x + (blockIdx.y << 4);
  lin = (lin & 7) * 64 + (lin >> 3);
  const int q0 = (lin & 15) * 64;
  const int bh = lin >> 4, b = bh >> 3, h = bh & 7;

  const short* Qg = Qg_ + ((long)(b * 1024 + q0)) * 1024 + h * 128;
  const short* Kg = Kg_ + ((long)b * 1024) * 1024 + h * 128;
  const short* Vg = V8T + (long)bh * 131072;   // [128 g][1024 s]

  const int srow = t >> 2;
  const int sgc = (((t & 3) ^ ((t >> 3) & 3)) << 3);  // pre-swizzled src chunk
  const int wbase = wave * 512;          // wave-uniform stage base (shorts)
  const int swzo = ((lhi ^ ((llo >> 1) & 3)) << 3);   // swizzled frag chunk
  const int arow = (wave * 16 + llo) * 32 + swzo;     // Q / P frag read

#pragma unroll
  for (int kk = 0; kk < 4; kk++)
    glds16(Qg + (long)srow * 1024 + kk * 32 + sgc, Qs + kk * 2048 + wbase);

  f32x4 o[8];
  float mR[4], lR[4];
#pragma unroll
  for (int i = 0; i < 8; i++) o[i] = f32x4{0.f, 0.f, 0.f, 0.f};
#pragma unroll
  for (int r = 0; r < 4; r++) { mR[r] = -1e30f; lR[r] = 0.f; }

  for (int it = 0; it < 8; it++) {
    const int kt0 = it * 128;
#pragma unroll
    for (int kk = 0; kk < 4; kk++) {
      glds16(Kg + (long)(kt0 + srow) * 1024 + kk * 32 + sgc,
             Ks + kk * 4096 + wbase);
      glds16(Kg + (long)(kt0 + 64 + srow) * 1024 + kk * 32 + sgc,
             Ks + kk * 4096 + 2048 + wbase);
      glds16(Vg + (long)srow * 1024 + kt0 + kk * 32 + sgc,
             Vs + kk * 4096 + wbase);
      glds16(Vg + (long)(64 + srow) * 1024 + kt0 + kk * 32 + sgc,
             Vs + kk * 4096 + 2048 + wbase);
    }
    __syncthreads();

    f32x4 s[8];
#pragma unroll
    for (int i = 0; i < 8; i++) s[i] = f32x4{0.f, 0.f, 0.f, 0.f};
#pragma unroll
    for (int kk = 0; kk < 4; kk++) {
      bf16x8 aq = *(const bf16x8*)(Qs + kk * 2048 + arow);
#pragma unroll
      for (int ct = 0; ct < 8; ct++) {
        bf16x8 bk = *(const bf16x8*)(Ks + kk * 4096 + (ct * 16 + llo) * 32 + swzo);
        s[ct] = __builtin_amdgcn_mfma_f32_16x16x32_bf16(aq, bk, s[ct], 0, 0, 0);
      }
    }
    // scores already scaled by SC*log2e (folded into Q); exp2 domain
    float mt[4];
#pragma unroll
    for (int r = 0; r < 4; r++) {
      float m = s[0][r];
#pragma unroll
      for (int ct = 1; ct < 8; ct++) m = fmaxf(m, s[ct][r]);
      m = fmaxf(m, __shfl_xor(m, 1));
      m = fmaxf(m, __shfl_xor(m, 2));
      m = fmaxf(m, __shfl_xor(m, 4));
      m = fmaxf(m, __shfl_xor(m, 8));
      mt[r] = m;
    }
    // defer-max: only rescale when max grew by > 8 (P bounded by 2^8)
    bool need = (mt[0] > mR[0] + 8.f) | (mt[1] > mR[1] + 8.f) |
                (mt[2] > mR[2] + 8.f) | (mt[3] > mR[3] + 8.f);
    if (__any(need)) {
      float alpha[4];
#pragma unroll
      for (int r = 0; r < 4; r++) {
        const float mn = fmaxf(mR[r], mt[r]);
        alpha[r] = __builtin_amdgcn_exp2f(mR[r] - mn);
        mR[r] = mn;
        lR[r] *= alpha[r];
      }
#pragma unroll
      for (int ct = 0; ct < 8; ct++)
#pragma unroll
        for (int r = 0; r < 4; r++) o[ct][r] *= alpha[r];
    }
#pragma unroll
    for (int ct = 0; ct < 8; ct++)
#pragma unroll
      for (int r = 0; r < 4; r++)
        s[ct][r] = __builtin_amdgcn_exp2f(s[ct][r] - mR[r]);
#pragma unroll
    for (int r = 0; r < 4; r++) {
      float ls = s[0][r];
#pragma unroll
      for (int ct = 1; ct < 8; ct++) ls += s[ct][r];
      ls += __shfl_xor(ls, 1);
      ls += __shfl_xor(ls, 2);
      ls += __shfl_xor(ls, 4);
      ls += __shfl_xor(ls, 8);
      lR[r] += ls;
    }
    __syncthreads();

    // P -> Ks rows 0..63, swizzled slots (col' matches swizzled P-read)
#pragma unroll
    for (int ct = 0; ct < 8; ct++) {
      const int chunk = ((ct & 1) << 1) | (llo >> 3);
      const int cl = llo & 7;
#pragma unroll
      for (int r = 0; r < 4; r++) {
        const int row = wave * 16 + lhi * 4 + r;
        const int xr = ((lhi << 1) | (r >> 1)) & 3;
        Ks[(ct >> 1) * 4096 + row * 32 + (((chunk ^ xr) << 3) | cl)] = f2bs(s[ct][r]);
      }
    }
    __syncthreads();

#pragma unroll
    for (int kk = 0; kk < 4; kk++) {
      bf16x8 ap = *(const bf16x8*)(Ks + kk * 4096 + arow);
#pragma unroll
      for (int ct = 0; ct < 8; ct++) {
        bf16x8 bv = *(const bf16x8*)(Vs + kk * 4096 + (ct * 16 + llo) * 32 + swzo);
        o[ct] = __builtin_amdgcn_mfma_f32_16x16x32_bf16(ap, bv, o[ct], 0, 0, 0);
      }
    }
    __syncthreads();
  }

  float inv[4];
#pragma unroll
  for (int r = 0; r < 4; r++) inv[r] = 1.0f / lR[r];
#pragma unroll
  for (int ct = 0; ct < 8; ct++) {
#pragma unroll
    for (int r = 0; r < 4; r++) {
      const int row = q0 + wave * 16 + lhi * 4 + r;
      const long idx = ((long)(b * 8 + h) * 1024 + row) * 128 + ct * 16 + llo;
      x1[idx] = xg[idx] + o[ct][r] * inv[r];
    }
  }
}

// ======================================================================
// 256x256 8-phase bf16 GEMM (T1 XCD swizzle + T2 swizzle + T3/T4 counted
// vmcnt + T5 setprio). 512 thr = 8 waves (2M x 4N), per-wave out 128x64,
// BK=64 (2 K-halves). LDS 128 KiB STATIC. One trailing barrier per phase.
// Epilogues: E_GELU (bias+GELU->bf16), E_QKV (bias->bf16; z==0 scaled by
// SC*log2e; z==2 -> transposed write into V8T head layout via aux),
// E_PART (f32 partial, direct stores; balanced across z).
// Per-z offsets: A += z*azk, Bt += z*bzk (shorts), bias += z*biasl.
// Requires NT=K/64 even, >=4; grid blocks %8 == 0.
// ======================================================================
enum { E_GELU = 0, E_QKV = 1, E_PART = 2 };

#define MF16(va, vb, vc) __builtin_amdgcn_mfma_f32_16x16x32_bf16(va, vb, vc, 0, 0, 0)
#define VMW(n) asm volatile("s_waitcnt vmcnt(" #n ")" ::: "memory")
#define NOPS ((void)0)

#define STAGE_A(BUF, KH, KB) do {                                          \
    glds16(Ag + (KB), smem + ((BUF) * 2 + (KH)) * 8192 + wofs);            \
    glds16(Ag2 + (KB), smem + ((BUF) * 2 + (KH)) * 8192 + 4096 + wofs);    \
  } while (0)
#define STAGE_B(BUF, KH, KB) do {                                          \
    glds16(Bg + (KB), smem + 32768 + ((BUF) * 2 + (KH)) * 8192 + wofs);    \
    glds16(Bg2 + (KB), smem + 32768 + ((BUF) * 2 + (KH)) * 8192 + 4096 + wofs); \
  } while (0)

// LOADB=1 -> load vb0..vb3 (B frags) this phase; LOADB=0 -> reuse.
#define PHASE(RH, KH, BUF, LOADB, STAGE_STMT, WAIT_STMT)                   \
  {                                                                        \
    const short* Ar_ = smem + ((BUF) * 2 + (KH)) * 8192 + aoff + (RH) * 2048; \
    bf16x8 a0 = *(const bf16x8*)(Ar_);                                     \
    bf16x8 a1 = *(const bf16x8*)(Ar_ + 512);                               \
    bf16x8 a2 = *(const bf16x8*)(Ar_ + 1024);                              \
    bf16x8 a3 = *(const bf16x8*)(Ar_ + 1536);                              \
    if (LOADB) {                                                           \
      const short* Br_ = smem + 32768 + ((BUF) * 2 + (KH)) * 8192 + boff;  \
      vb0 = *(const bf16x8*)(Br_);                                         \
      vb1 = *(const bf16x8*)(Br_ + 512);                                   \
      vb2 = *(const bf16x8*)(Br_ + 1024);                                  \
      vb3 = *(const bf16x8*)(Br_ + 1536);                                  \
    }                                                                      \
    STAGE_STMT;                                                            \
    __builtin_amdgcn_s_setprio(1);                                         \
    acc[(RH) * 4 + 0][0] = MF16(a0, vb0, acc[(RH) * 4 + 0][0]);            \
    acc[(RH) * 4 + 0][1] = MF16(a0, vb1, acc[(RH) * 4 + 0][1]);            \
    acc[(RH) * 4 + 0][2] = MF16(a0, vb2, acc[(RH) * 4 + 0][2]);            \
    acc[(RH) * 4 + 0][3] = MF16(a0, vb3, acc[(RH) * 4 + 0][3]);            \
    acc[(RH) * 4 + 1][0] = MF16(a1, vb0, acc[(RH) * 4 + 1][0]);            \
    acc[(RH) * 4 + 1][1] = MF16(a1, vb1, acc[(RH) * 4 + 1][1]);            \
    acc[(RH) * 4 + 1][2] = MF16(a1, vb2, acc[(RH) * 4 + 1][2]);            \
    acc[(RH) * 4 + 1][3] = MF16(a1, vb3, acc[(RH) * 4 + 1][3]);            \
    acc[(RH) * 4 + 2][0] = MF16(a2, vb0, acc[(RH) * 4 + 2][0]);            \
    acc[(RH) * 4 + 2][1] = MF16(a2, vb1, acc[(RH) * 4 + 2][1]);            \
    acc[(RH) * 4 + 2][2] = MF16(a2, vb2, acc[(RH) * 4 + 2][2]);            \
    acc[(RH) * 4 + 2][3] = MF16(a2, vb3, acc[(RH) * 4 + 2][3]);            \
    acc[(RH) * 4 + 3][0] = MF16(a3, vb0, acc[(RH) * 4 + 3][0]);            \
    acc[(RH) * 4 + 3][1] = MF16(a3, vb1, acc[(RH) * 4 + 3][1]);            \
    acc[(RH) * 4 + 3][2] = MF16(a3, vb2, acc[(RH) * 4 + 3][2]);            \
    acc[(RH) * 4 + 3][3] = MF16(a3, vb3, acc[(RH) * 4 + 3][3]);            \
    __builtin_amdgcn_s_setprio(0);                                         \
    WAIT_STMT;                                                             \
    __builtin_amdgcn_sched_barrier(0);                                     \
    __builtin_amdgcn_s_barrier();                                          \
    __builtin_amdgcn_sched_barrier(0);                                     \
  }

#define TILE8(T, BUF)                                                        \
  PHASE(0, 0, BUF, 1, STAGE_A(1 - (BUF), 1, ((T) + 1) * 64 + 32), NOPS);     \
  PHASE(1, 0, BUF, 0, STAGE_B(1 - (BUF), 1, ((T) + 1) * 64 + 32), VMW(8));   \
  PHASE(0, 1, BUF, 1, STAGE_A(BUF, 0, ((T) + 2) * 64), NOPS);                \
  PHASE(1, 1, BUF, 0, STAGE_B(BUF, 0, ((T) + 2) * 64), VMW(8))

template <int EPI>
__global__ __launch_bounds__(512, 2) void gemm256(
    const short* __restrict__ A, int lda, long azk,
    const short* __restrict__ Bt, int ldb, long bzk,
    const float* __restrict__ bias, long biasl,
    void* __restrict__ outp, long czl, int ldc,
    void* __restrict__ aux, int K) {
  __shared__ __align__(16) short smem[65536];  // 128 KiB static

  const int t = threadIdx.x;
  const int wave = t >> 6, lane = t & 63;
  const int llo = lane & 15, lhi = lane >> 4;
  const int wm = wave >> 2, wn = wave & 3;

  // XCD-chunked bijective remap: keep x-partners (shared A panel) on one XCD
  int lin = blockIdx.x + gridDim.x * (blockIdx.y + gridDim.y * blockIdx.z);
  const int nwg = gridDim.x * gridDim.y * gridDim.z;  // % 8 == 0
  lin = (lin & 7) * (nwg >> 3) + (lin >> 3);
  const int bx = lin % gridDim.x;
  const int rem = lin / gridDim.x;
  const int by = rem % gridDim.y;
  const int z = rem / gridDim.y;

  const int bm0 = by * 256, bn0 = bx * 256;
  A += (long)z * azk;
  Bt += (long)z * bzk;

  // staging constants: thread loads rows (srow, srow+128), chunk pre-swizzled
  const int srow = t >> 2;                                 // 0..127
  const int sgc = (((t & 3) ^ ((t >> 3) & 3)) << 3);       // source chunk (shorts)
  const short* Ag  = A  + (long)(bm0 + srow) * lda + sgc;
  const short* Ag2 = A  + (long)(bm0 + 128 + srow) * lda + sgc;
  const short* Bg  = Bt + (long)(bn0 + srow) * ldb + sgc;
  const short* Bg2 = Bt + (long)(bn0 + 128 + srow) * ldb + sgc;
  const int wofs = wave * 512;                             // wave-uniform LDS base

  // fragment read constants (rows within region are multiples of 16 + llo)
  const int swz = ((lhi ^ ((llo >> 1) & 3)) << 3);
  const int aoff = (wm * 128 + llo) * 32 + swz;            // + RH*2048 + rt*512
  const int boff = (wn * 64 + llo) * 32 + swz;             // + ct*512

  f32x4 acc[8][4];
#pragma unroll
  for (int i = 0; i < 8; i++)
#pragma unroll
    for (int j = 0; j < 4; j++) acc[i][j] = f32x4{0.f, 0.f, 0.f, 0.f};
  bf16x8 vb0, vb1, vb2, vb3;  // B frags, loaded at RH=0, reused at RH=1

  const int NT = K >> 6;  // even, >= 4

  // prologue: tile0 (both K-halves) + tile1 K-half0; keep newest 8 in flight
  STAGE_A(0, 0, 0);  STAGE_B(0, 0, 0);
  STAGE_A(0, 1, 32); STAGE_B(0, 1, 32);
  STAGE_A(1, 0, 64); STAGE_B(1, 0, 64);
  VMW(8);
  __builtin_amdgcn_sched_barrier(0);
  __builtin_amdgcn_s_barrier();
  __builtin_amdgcn_sched_barrier(0);

  for (int tt = 0; tt < NT - 2; tt += 2) {
    TILE8(tt, 0);
    TILE8(tt + 1, 1);
  }
  // tail tile NT-2 (buf 0): stage only tile NT-1's K-half1
  PHASE(0, 0, 0, 1, STAGE_A(1, 1, (NT - 1) * 64 + 32), NOPS);
  PHASE(1, 0, 0, 0, STAGE_B(1, 1, (NT - 1) * 64 + 32), VMW(8));
  PHASE(0, 1, 0, 1, NOPS, NOPS);
  PHASE(1, 1, 0, 0, NOPS, VMW(4));
  // tail tile NT-1 (buf 1): no staging
  PHASE(0, 0, 1, 1, NOPS, NOPS);
  PHASE(1, 0, 1, 0, NOPS, VMW(0));
  PHASE(0, 1, 1, 1, NOPS, NOPS);
  PHASE(1, 1, 1, 0, NOPS, NOPS);

  if (EPI == E_PART) {
    // f32 partial, direct stores
    float* P = (float*)outp + (long)z * czl;
#pragma unroll
    for (int ct = 0; ct < 4; ct++) {
      const int col = bn0 + wn * 64 + ct * 16 + llo;
#pragma unroll
      for (int rt = 0; rt < 8; rt++) {
#pragma unroll
        for (int r = 0; r < 4; r++) {
          const int row = bm0 + wm * 128 + rt * 16 + lhi * 4 + r;
          P[(long)row * ldc + col] = acc[rt][ct][r];
        }
      }
    }
  } else if (EPI == E_QKV && z == 2) {
    // V8 projection: transposed write into V8T[bh][g][s] via per-wave slab
    short* slab = smem + wave * 4352;   // [64 cols][68] shorts
    const int bb = bm0 >> 10, sbase = (bm0 & 1023) + wm * 128;
    float bv4[4];
#pragma unroll
    for (int ct = 0; ct < 4; ct++)
      bv4[ct] = bias[z * biasl + bn0 + wn * 64 + ct * 16 + llo];
    const int gcol = bn0 + wn * 64 + lane;
    short* dst0 = (short*)aux + ((long)(bb * 8 + (gcol >> 7))) * 131072 +
                  (long)(gcol & 127) * 1024 + sbase;
#pragma unroll
    for (int p = 0; p < 2; p++) {
#pragma unroll
      for (int rt4 = 0; rt4 < 4; rt4++) {
#pragma unroll
        for (int ct = 0; ct < 4; ct++) {
#pragma unroll
          for (int r = 0; r < 4; r++) {
            float v = acc[p * 4 + rt4][ct][r] + bv4[ct];
            slab[(ct * 16 + llo) * 68 + rt4 * 16 + lhi * 4 + r] = f2bs(v);
          }
        }
      }
#pragma unroll
      for (int j = 0; j < 8; j++)
        *(short8*)(dst0 + p * 64 + j * 8) = *(const short8*)&slab[lane * 68 + j * 8];
    }
  } else {
    // bias (+GELU/+Qscale) -> bf16 via per-wave LDS slab -> short8 stores
    short* C = (short*)outp + (long)z * czl;
    short* slab = smem + wave * 4864;   // [64 rows][76 cols] shorts
    float bv4[4];
#pragma unroll
    for (int ct = 0; ct < 4; ct++)
      bv4[ct] = bias[z * biasl + bn0 + wn * 64 + ct * 16 + llo];
    const int rl0 = lane >> 3, cb8 = (lane & 7) << 3;
    const short* srd = slab + rl0 * 76 + cb8;
    short* Cw = C + (long)(bm0 + wm * 128 + rl0) * ldc + bn0 + wn * 64 + cb8;
#pragma unroll
    for (int p = 0; p < 2; p++) {
#pragma unroll
      for (int rt4 = 0; rt4 < 4; rt4++) {
#pragma unroll
        for (int ct = 0; ct < 4; ct++) {
#pragma unroll
          for (int r = 0; r < 4; r++) {
            float v = acc[p * 4 + rt4][ct][r] + bv4[ct];
            if (EPI == E_GELU)
              v = 0.5f * v * (1.0f + erff(v * 0.70710678118654752f));
            if (EPI == E_QKV && z == 0)
              v *= 0.12751744476582f;  // (1/sqrt(128)) * log2(e)
            slab[(rt4 * 16 + lhi * 4 + r) * 76 + ct * 16 + llo] = f2bs(v);
          }
        }
      }
#pragma unroll
      for (int j = 0; j < 8; j++) {
        short8 v = *(const short8*)(srd + j * 8 * 76);
        *(short8*)(Cw + ((long)p * 64 + j * 8) * ldc) = v;
      }
    }
  }
}

// ---------- launch ----------
extern "C" void kernel_launch(void* const* d_in, const int* in_sizes, int n_in,
                              void* d_out, int out_size, void* d_ws, size_t ws_size,
                              hipStream_t stream) {
  const float* x   = (const float*)d_in[0];
  // d_in[1] = mask (int32) — unused in infer path
  const float* g1  = (const float*)d_in[2];
  const float* b1  = (const float*)d_in[3];
  const float* Wq  = (const float*)d_in[4];
  const float* bq  = (const float*)d_in[5];
  const float* Wk  = (const float*)d_in[6];
  const float* bk  = (const float*)d_in[7];
  const float* Wv  = (const float*)d_in[8];
  const float* bv  = (const float*)d_in[9];
  const float* g2  = (const float*)d_in[10];
  const float* b2  = (const float*)d_in[11];
  const float* W1  = (const float*)d_in[12];
  const float* bw1 = (const float*)d_in[13];
  const float* W2  = (const float*)d_in[14];
  const float* bw2 = (const float*)d_in[15];

  char* ws = (char*)d_ws;
  const long MB = 1024 * 1024;
  // layout (peak 137MB; ws >= 189MB proven in round 5):
  float* bQKV  = (float*)(ws);            // [3][1024] f32: bq | bk | bv8
  float* x1    = (float*)(ws + 1 * MB);   // [4096,1024] f32  [1,17)
  short* wqT   = (short*)(ws + 17 * MB);  // [17,19)
  short* wkT   = (short*)(ws + 19 * MB);  // [19,21)  contiguous with wqT
  short* wv8T  = (short*)(ws + 21 * MB);  // [21,23)  contiguous (z*2MB)
  short* xn    = (short*)(ws + 23 * MB);  // [23,31)
  short* Q     = (short*)(ws + 31 * MB);  // [31,39)
  short* Kb    = (short*)(ws + 39 * MB);  // [39,47)  contiguous with Q
  short* V8T   = (short*)(ws + 47 * MB);  // [32][128][1024] bf16 [47,55)
  // FFN overlay (attention scratch dead by then):
  short* xn2  = (short*)(ws + 17 * MB);  // [17,25)
  short* Hb   = (short*)(ws + 25 * MB);  // [25,57)
  short* w1T  = (short*)(ws + 57 * MB);  // [57,65)
  short* w2T  = (short*)(ws + 65 * MB);  // [65,73)
  float* part = (float*)(ws + 73 * MB);  // [4][4096,1024] f32 [73,137)

  // fused prep: LN1 + Wq/Wk/W1/W2 transposes + wv8 + bv8 + bias copies
  prep_k<<<6918, 256, 0, stream>>>(x, g1, b1, xn,
                                   Wq, wqT, Wk, wkT, Wv, wv8T,
                                   W1, w1T, W2, w2T,
                                   bq, bk, bv, bQKV);

  // QKV: z=0 -> Q (pre-scaled), z=1 -> Kb, z=2 -> V8T (transposed). K=1024.
  gemm256<E_QKV><<<dim3(4, 16, 3), 512, 0, stream>>>(
      xn, 1024, 0, wqT, 1024, 1048576, bQKV, 1024,
      Q, 4194304, 1024, V8T, 1024);

  // fused attention: scores+softmax+PV8+head-sum+residual -> x1
  flash_k<<<dim3(16, 32), 256, 0, stream>>>(Q, Kb, V8T, x, x1);

  // ---- FFN phase ----
  ln_k<<<4096, 256, 0, stream>>>(x1, g2, b2, xn2);

  // FFN1 + exact GELU -> Hb (bf16). K=1024.
  gemm256<E_GELU><<<dim3(16, 16, 1), 512, 0, stream>>>(
      xn2, 1024, 0, w1T, 1024, 0, bw1, 0,
      Hb, 0, 4096, nullptr, 1024);

  // FFN2 split-K=4: f32 partials (balanced; residual+bias in reduce4).
  gemm256<E_PART><<<dim3(4, 16, 4), 512, 0, stream>>>(
      Hb, 4096, 1024, w2T, 4096, 1024, nullptr, 0,
      part, 4194304, 1024, nullptr, 1024);

  reduce4_k<<<4096, 256, 0, stream>>>(part, x1, bw2, (float*)d_out);
}

// Round 11
// 348.118 us; speedup vs baseline: 1.0707x; 1.0154x over previous
//
#include <hip/hip_runtime.h>
#include <hip/hip_bf16.h>
#include <math.h>

// ---------- types ----------
typedef __attribute__((ext_vector_type(8))) short   short8;
typedef __attribute__((ext_vector_type(4))) short   short4v;
typedef __attribute__((ext_vector_type(8))) __bf16  bf16x8;
typedef __attribute__((ext_vector_type(4))) float   f32x4;

typedef const __attribute__((address_space(1))) void cgv_t;
typedef __attribute__((address_space(3))) void lv_t;

__device__ __forceinline__ float bs2f(short s) {
  unsigned int u = ((unsigned int)(unsigned short)s) << 16;
  return __builtin_bit_cast(float, u);
}
__device__ __forceinline__ short f2bs(float f) {
  __hip_bfloat16 h = __float2bfloat16(f);  // RNE
  return __builtin_bit_cast(short, h);
}
// async global->LDS, 16B per lane; lds base must be wave-uniform
__device__ __forceinline__ void glds16(const short* g, short* l) {
  __builtin_amdgcn_global_load_lds((cgv_t*)g, (lv_t*)l, 16, 0, 0);
}

// B=4, S=1024, D=1024, H=8, FF=4096, DK=128. I/O f32; internals bf16.
// Head-sum trick: attn[s,g] = sum_k P[s,k] * V8[k,g], V8 = xn @ Wv8,
// Wv8[:,r] = sum_{e<8} Wv[:,8r+e]. Attention fused flash-style.
// Q is pre-scaled by (1/sqrt(128))*log2(e) at the QKV epilogue, so the
// flash softmax runs entirely in the exp2 domain (raw v_exp_f32).
// Reference's raw reshape: (b,h,s,gg) attn value lands at x1 flat index
// ((b*8+h)*1024+s)*128+gg (verified round 6/8).

// ---------- prep device bodies ----------
// transpose unit descriptor: out[C][R] = bf16(in[R][C]), 64x64 tile (bx,by)
struct TrU { const float* in; short* out; int R, C, bx, by; };

__device__ __forceinline__ TrU tr_decode(
    int u,
    const float* Wq, short* wqT, const float* Wk, short* wkT,
    const float* W1, short* w1T, const float* W2, short* w2T) {
  TrU s;
  if (u < 1024)      { s.in = W1; s.out = w1T; s.R = 1024; s.C = 4096; s.bx = u & 63; s.by = u >> 6; }
  else if (u < 2048) { int v = u - 1024; s.in = W2; s.out = w2T; s.R = 4096; s.C = 1024; s.bx = v & 15; s.by = v >> 4; }
  else if (u < 2304) { int v = u - 2048; s.in = Wq; s.out = wqT; s.R = 1024; s.C = 1024; s.bx = v & 15; s.by = v >> 4; }
  else               { int v = u - 2304; s.in = Wk; s.out = wkT; s.R = 1024; s.C = 1024; s.bx = v & 15; s.by = v >> 4; }
  return s;
}

// pair-pipelined double transpose: all 8 global loads issued up-front,
// both LDS writes, ONE sync, both read+store phases.
__device__ __forceinline__ void tr2_body(const TrU& A, const TrU& B,
                                         short* T0, short* T1) {
  const int t = threadIdx.x;
  const int rr = t >> 4, cc = (t & 15) << 2;
  f32x4 va[4], vb[4];
#pragma unroll
  for (int h = 0; h < 4; h++)
    va[h] = *(const f32x4*)(A.in + (long)(A.by * 64 + rr + h * 16) * A.C + A.bx * 64 + cc);
#pragma unroll
  for (int h = 0; h < 4; h++)
    vb[h] = *(const f32x4*)(B.in + (long)(B.by * 64 + rr + h * 16) * B.C + B.bx * 64 + cc);
#pragma unroll
  for (int h = 0; h < 4; h++)
#pragma unroll
    for (int e = 0; e < 4; e++) {
      T0[(rr + h * 16) * 72 + cc + e] = f2bs(va[h][e]);
      T1[(rr + h * 16) * 72 + cc + e] = f2bs(vb[h][e]);
    }
  __syncthreads();
  const int cr = t >> 3, rs = (t & 7) << 3;
#pragma unroll
  for (int hf = 0; hf < 2; hf++) {
    const int c = cr + hf * 32;
    short8 v0, v1;
#pragma unroll
    for (int e = 0; e < 8; e++) { v0[e] = T0[(rs + e) * 72 + c]; v1[e] = T1[(rs + e) * 72 + c]; }
    *(short8*)(A.out + (long)(A.bx * 64 + c) * A.R + A.by * 64 + rs) = v0;
    *(short8*)(B.out + (long)(B.bx * 64 + c) * B.R + B.by * 64 + rs) = v1;
  }
}

// wv8T[r][k] = bf16( sum_{e<8} Wv[k][8r+e] ); 64x64 tile
__device__ __forceinline__ void wv8_body(const float* __restrict__ Wv,
                                         short* __restrict__ out,
                                         int bx, int by, short* T) {
  const int r0 = bx * 64, k0 = by * 64;
  const int t = threadIdx.x;
  const int wave = t >> 6, lane = t & 63;
  const int r = r0 + lane;
#pragma unroll 4
  for (int i = 0; i < 16; i++) {
    const int k = k0 + wave * 16 + i;
    const float* src = Wv + (long)k * 8192 + 8 * r;
    f32x4 a = *(const f32x4*)src;
    f32x4 b = *(const f32x4*)(src + 4);
    float s = (a[0] + a[1] + a[2] + a[3]) + (b[0] + b[1] + b[2] + b[3]);
    T[lane * 72 + wave * 16 + i] = f2bs(s);
  }
  __syncthreads();
  const int rr = t >> 3, kc = (t & 7) << 3;
#pragma unroll
  for (int half = 0; half < 2; half++) {
    const int rl = rr + half * 32;
    *(short8*)(out + (long)(r0 + rl) * 1024 + k0 + kc) = *(const short8*)&T[rl * 72 + kc];
  }
}

// layernorm row of 1024; f32 in/params; bf16 out
__device__ __forceinline__ void ln_body(const float* __restrict__ in,
                                        const float* __restrict__ g,
                                        const float* __restrict__ b,
                                        short* __restrict__ out, int row,
                                        float* rs, float* rq) {
  const int t = threadIdx.x;
  const long base = (long)row * 1024 + t * 4;
  f32x4 f = *(const f32x4*)(in + base);
  float v[4] = {f[0], f[1], f[2], f[3]};
  float s1 = v[0] + v[1] + v[2] + v[3];
  float s2 = v[0]*v[0] + v[1]*v[1] + v[2]*v[2] + v[3]*v[3];
#pragma unroll
  for (int off = 32; off; off >>= 1) {
    s1 += __shfl_xor(s1, off);
    s2 += __shfl_xor(s2, off);
  }
  if ((t & 63) == 0) { rs[t >> 6] = s1; rq[t >> 6] = s2; }
  __syncthreads();
  s1 = rs[0] + rs[1] + rs[2] + rs[3];
  s2 = rq[0] + rq[1] + rq[2] + rq[3];
  const float mean = s1 * (1.0f / 1024.0f);
  const float var  = s2 * (1.0f / 1024.0f) - mean * mean;
  const float rstd = rsqrtf(var + 1e-5f);
  f32x4 gv = *(const f32x4*)(g + t * 4);
  f32x4 bv = *(const f32x4*)(b + t * 4);
  short4v o;
#pragma unroll
  for (int i = 0; i < 4; i++)
    o[i] = f2bs((v[i] - mean) * rstd * gv[i] + bv[i]);
  *(short4v*)(out + base) = o;
}

// ---------- fused prep ----------
// [0,1280): tr pairs (units 2b, 2b+1 of 2560: W1|W2|Wq|Wk)
// [1280,1536): wv8 tiles | [1536,1540): bv8 | 1540,1541: bq/bk copy
// [1542, 5638): LN1 rows. Total 5638 blocks.
__global__ __launch_bounds__(256) void prep_k(
    const float* __restrict__ x, const float* __restrict__ g1,
    const float* __restrict__ b1, short* __restrict__ xn,
    const float* __restrict__ Wq, short* __restrict__ wqT,
    const float* __restrict__ Wk, short* __restrict__ wkT,
    const float* __restrict__ Wv, short* __restrict__ wv8T,
    const float* __restrict__ W1, short* __restrict__ w1T,
    const float* __restrict__ W2, short* __restrict__ w2T,
    const float* __restrict__ bq, const float* __restrict__ bk,
    const float* __restrict__ bv, float* __restrict__ bQKV) {
  __shared__ __align__(16) short T[2][64 * 72];
  __shared__ float rs[4], rq[4];
  const int t = threadIdx.x;
  int bid = blockIdx.x;
  if (bid < 1280) {
    TrU A = tr_decode(bid * 2,     Wq, wqT, Wk, wkT, W1, w1T, W2, w2T);
    TrU B = tr_decode(bid * 2 + 1, Wq, wqT, Wk, wkT, W1, w1T, W2, w2T);
    tr2_body(A, B, T[0], T[1]);
    return;
  }
  bid -= 1280;
  if (bid < 256) { wv8_body(Wv, wv8T, bid & 15, bid >> 4, T[0]); return; }
  bid -= 256;
  if (bid < 4) {
    const int r = bid * 256 + t;
    f32x4 a = *(const f32x4*)(bv + 8 * r);
    f32x4 b = *(const f32x4*)(bv + 8 * r + 4);
    bQKV[2048 + r] = (a[0] + a[1] + a[2] + a[3]) + (b[0] + b[1] + b[2] + b[3]);
    return;
  }
  bid -= 4;
  if (bid == 0) { *(f32x4*)(bQKV + t * 4) = *(const f32x4*)(bq + t * 4); return; }
  if (bid == 1) { *(f32x4*)(bQKV + 1024 + t * 4) = *(const f32x4*)(bk + t * 4); return; }
  ln_body(x, g1, b1, xn, bid - 2, rs, rq);
}

// ---------- layernorm kernel (2nd LN: x1 -> xn2) ----------
__global__ __launch_bounds__(256) void ln_k(const float* __restrict__ in,
                                            const float* __restrict__ g,
                                            const float* __restrict__ b,
                                            short* __restrict__ out) {
  __shared__ float rs[4], rq[4];
  ln_body(in, g, b, out, blockIdx.x, rs, rq);
}

// ---------- split-K=4 reduce: d_out = p0..p3 + x1 + bias ----------
__global__ __launch_bounds__(256) void reduce4_k(const float* __restrict__ p,
                                                 const float* __restrict__ x1,
                                                 const float* __restrict__ bias,
                                                 float* __restrict__ out) {
  const int t = threadIdx.x;
  const long base = (long)blockIdx.x * 1024 + t * 4;
  f32x4 a = *(const f32x4*)(p + base);
  f32x4 b = *(const f32x4*)(p + 4194304 + base);
  f32x4 c = *(const f32x4*)(p + 8388608 + base);
  f32x4 d = *(const f32x4*)(p + 12582912 + base);
  f32x4 e = *(const f32x4*)(x1 + base);
  f32x4 g = *(const f32x4*)(bias + t * 4);
  *(f32x4*)(out + base) = a + b + c + d + e + g;
}

// ---------- fused flash attention (+head-sum + residual) ----------
// Q pre-scaled by SC*log2e; softmax in exp2 domain; defer-max (THR=8,
// exact: m cancels in o/l). XCD swizzle: XCD r owns bh in [4r,4r+4) so
// its K/V working set (2MB) is L2-resident. T2 XOR swizzle on LDS slabs.
__global__ __launch_bounds__(256, 2) void flash_k(
    const short* __restrict__ Qg_, const short* __restrict__ Kg_,
    const short* __restrict__ V8T, const float* __restrict__ xg,
    float* __restrict__ x1) {
  __shared__ __align__(16) short smem[40960];  // 80 KB exactly
  short* Qs = smem;            // 4 * [64][32]  (slab 2048 shorts)
  short* Ks = smem + 8192;     // 4 * [128][32] (slab 4096); P reuses rows 0..63
  short* Vs = smem + 24576;    // 4 * [128][32]

  const int t = threadIdx.x;
  const int wave = t >> 6, lane = t & 63;
  const int llo = lane & 15, lhi = lane >> 4;

  // XCD-grouped remap: 512 blocks, XCD r <- bh in [4r, 4r+4), all 16 q-tiles
  int lin = blockIdx.x + (blockIdx.y << 4);
  lin = (lin & 7) * 64 + (lin >> 3);
  const int q0 = (lin & 15) * 64;
  const int bh = lin >> 4, b = bh >> 3, h = bh & 7;

  const short* Qg = Qg_ + ((long)(b * 1024 + q0)) * 1024 + h * 128;
  const short* Kg = Kg_ + ((long)b * 1024) * 1024 + h * 128;
  const short* Vg = V8T + (long)bh * 131072;   // [128 g][1024 s]

  const int srow = t >> 2;
  const int sgc = (((t & 3) ^ ((t >> 3) & 3)) << 3);  // pre-swizzled src chunk
  const int wbase = wave * 512;          // wave-uniform stage base (shorts)
  const int swzo = ((lhi ^ ((llo >> 1) & 3)) << 3);   // swizzled frag chunk
  const int arow = (wave * 16 + llo) * 32 + swzo;     // Q / P frag read

#pragma unroll
  for (int kk = 0; kk < 4; kk++)
    glds16(Qg + (long)srow * 1024 + kk * 32 + sgc, Qs + kk * 2048 + wbase);

  f32x4 o[8];
  float mR[4], lR[4];
#pragma unroll
  for (int i = 0; i < 8; i++) o[i] = f32x4{0.f, 0.f, 0.f, 0.f};
#pragma unroll
  for (int r = 0; r < 4; r++) { mR[r] = -1e30f; lR[r] = 0.f; }

  for (int it = 0; it < 8; it++) {
    const int kt0 = it * 128;
#pragma unroll
    for (int kk = 0; kk < 4; kk++) {
      glds16(Kg + (long)(kt0 + srow) * 1024 + kk * 32 + sgc,
             Ks + kk * 4096 + wbase);
      glds16(Kg + (long)(kt0 + 64 + srow) * 1024 + kk * 32 + sgc,
             Ks + kk * 4096 + 2048 + wbase);
      glds16(Vg + (long)srow * 1024 + kt0 + kk * 32 + sgc,
             Vs + kk * 4096 + wbase);
      glds16(Vg + (long)(64 + srow) * 1024 + kt0 + kk * 32 + sgc,
             Vs + kk * 4096 + 2048 + wbase);
    }
    __syncthreads();

    f32x4 s[8];
#pragma unroll
    for (int i = 0; i < 8; i++) s[i] = f32x4{0.f, 0.f, 0.f, 0.f};
#pragma unroll
    for (int kk = 0; kk < 4; kk++) {
      bf16x8 aq = *(const bf16x8*)(Qs + kk * 2048 + arow);
#pragma unroll
      for (int ct = 0; ct < 8; ct++) {
        bf16x8 bk = *(const bf16x8*)(Ks + kk * 4096 + (ct * 16 + llo) * 32 + swzo);
        s[ct] = __builtin_amdgcn_mfma_f32_16x16x32_bf16(aq, bk, s[ct], 0, 0, 0);
      }
    }
    // scores already scaled by SC*log2e (folded into Q); exp2 domain
    float mt[4];
#pragma unroll
    for (int r = 0; r < 4; r++) {
      float m = s[0][r];
#pragma unroll
      for (int ct = 1; ct < 8; ct++) m = fmaxf(m, s[ct][r]);
      m = fmaxf(m, __shfl_xor(m, 1));
      m = fmaxf(m, __shfl_xor(m, 2));
      m = fmaxf(m, __shfl_xor(m, 4));
      m = fmaxf(m, __shfl_xor(m, 8));
      mt[r] = m;
    }
    // defer-max: only rescale when max grew by > 8 (P bounded by 2^8)
    bool need = (mt[0] > mR[0] + 8.f) | (mt[1] > mR[1] + 8.f) |
                (mt[2] > mR[2] + 8.f) | (mt[3] > mR[3] + 8.f);
    if (__any(need)) {
      float alpha[4];
#pragma unroll
      for (int r = 0; r < 4; r++) {
        const float mn = fmaxf(mR[r], mt[r]);
        alpha[r] = __builtin_amdgcn_exp2f(mR[r] - mn);
        mR[r] = mn;
        lR[r] *= alpha[r];
      }
#pragma unroll
      for (int ct = 0; ct < 8; ct++)
#pragma unroll
        for (int r = 0; r < 4; r++) o[ct][r] *= alpha[r];
    }
#pragma unroll
    for (int ct = 0; ct < 8; ct++)
#pragma unroll
      for (int r = 0; r < 4; r++)
        s[ct][r] = __builtin_amdgcn_exp2f(s[ct][r] - mR[r]);
#pragma unroll
    for (int r = 0; r < 4; r++) {
      float ls = s[0][r];
#pragma unroll
      for (int ct = 1; ct < 8; ct++) ls += s[ct][r];
      ls += __shfl_xor(ls, 1);
      ls += __shfl_xor(ls, 2);
      ls += __shfl_xor(ls, 4);
      ls += __shfl_xor(ls, 8);
      lR[r] += ls;
    }
    __syncthreads();

    // P -> Ks rows 0..63, swizzled slots (col' matches swizzled P-read)
#pragma unroll
    for (int ct = 0; ct < 8; ct++) {
      const int chunk = ((ct & 1) << 1) | (llo >> 3);
      const int cl = llo & 7;
#pragma unroll
      for (int r = 0; r < 4; r++) {
        const int row = wave * 16 + lhi * 4 + r;
        const int xr = ((lhi << 1) | (r >> 1)) & 3;
        Ks[(ct >> 1) * 4096 + row * 32 + (((chunk ^ xr) << 3) | cl)] = f2bs(s[ct][r]);
      }
    }
    __syncthreads();

#pragma unroll
    for (int kk = 0; kk < 4; kk++) {
      bf16x8 ap = *(const bf16x8*)(Ks + kk * 4096 + arow);
#pragma unroll
      for (int ct = 0; ct < 8; ct++) {
        bf16x8 bv = *(const bf16x8*)(Vs + kk * 4096 + (ct * 16 + llo) * 32 + swzo);
        o[ct] = __builtin_amdgcn_mfma_f32_16x16x32_bf16(ap, bv, o[ct], 0, 0, 0);
      }
    }
    __syncthreads();
  }

  float inv[4];
#pragma unroll
  for (int r = 0; r < 4; r++) inv[r] = 1.0f / lR[r];
#pragma unroll
  for (int ct = 0; ct < 8; ct++) {
#pragma unroll
    for (int r = 0; r < 4; r++) {
      const int row = q0 + wave * 16 + lhi * 4 + r;
      const long idx = ((long)(b * 8 + h) * 1024 + row) * 128 + ct * 16 + llo;
      x1[idx] = xg[idx] + o[ct][r] * inv[r];
    }
  }
}

// ======================================================================
// 256x256 8-phase bf16 GEMM (T1 XCD swizzle + T2 swizzle + T3/T4 counted
// vmcnt + T5 setprio). 512 thr = 8 waves (2M x 4N), per-wave out 128x64,
// BK=64 (2 K-halves). LDS 128 KiB STATIC. One trailing barrier per phase.
// Epilogues: E_GELU (bias+GELU->bf16), E_QKV (bias->bf16; z==0 scaled by
// SC*log2e; z==2 -> transposed write into V8T head layout via aux),
// E_PART (f32 partial, direct stores; balanced across z).
// Per-z offsets: A += z*azk, Bt += z*bzk (shorts), bias += z*biasl.
// Requires NT=K/64 even, >=4; grid blocks %8 == 0.
// ======================================================================
enum { E_GELU = 0, E_QKV = 1, E_PART = 2 };

#define MF16(va, vb, vc) __builtin_amdgcn_mfma_f32_16x16x32_bf16(va, vb, vc, 0, 0, 0)
#define VMW(n) asm volatile("s_waitcnt vmcnt(" #n ")" ::: "memory")
#define NOPS ((void)0)

#define STAGE_A(BUF, KH, KB) do {                                          \
    glds16(Ag + (KB), smem + ((BUF) * 2 + (KH)) * 8192 + wofs);            \
    glds16(Ag2 + (KB), smem + ((BUF) * 2 + (KH)) * 8192 + 4096 + wofs);    \
  } while (0)
#define STAGE_B(BUF, KH, KB) do {                                          \
    glds16(Bg + (KB), smem + 32768 + ((BUF) * 2 + (KH)) * 8192 + wofs);    \
    glds16(Bg2 + (KB), smem + 32768 + ((BUF) * 2 + (KH)) * 8192 + 4096 + wofs); \
  } while (0)

// LOADB=1 -> load vb0..vb3 (B frags) this phase; LOADB=0 -> reuse.
#define PHASE(RH, KH, BUF, LOADB, STAGE_STMT, WAIT_STMT)                   \
  {                                                                        \
    const short* Ar_ = smem + ((BUF) * 2 + (KH)) * 8192 + aoff + (RH) * 2048; \
    bf16x8 a0 = *(const bf16x8*)(Ar_);                                     \
    bf16x8 a1 = *(const bf16x8*)(Ar_ + 512);                               \
    bf16x8 a2 = *(const bf16x8*)(Ar_ + 1024);                              \
    bf16x8 a3 = *(const bf16x8*)(Ar_ + 1536);                              \
    if (LOADB) {                                                           \
      const short* Br_ = smem + 32768 + ((BUF) * 2 + (KH)) * 8192 + boff;  \
      vb0 = *(const bf16x8*)(Br_);                                         \
      vb1 = *(const bf16x8*)(Br_ + 512);                                   \
      vb2 = *(const bf16x8*)(Br_ + 1024);                                  \
      vb3 = *(const bf16x8*)(Br_ + 1536);                                  \
    }                                                                      \
    STAGE_STMT;                                                            \
    __builtin_amdgcn_s_setprio(1);                                         \
    acc[(RH) * 4 + 0][0] = MF16(a0, vb0, acc[(RH) * 4 + 0][0]);            \
    acc[(RH) * 4 + 0][1] = MF16(a0, vb1, acc[(RH) * 4 + 0][1]);            \
    acc[(RH) * 4 + 0][2] = MF16(a0, vb2, acc[(RH) * 4 + 0][2]);            \
    acc[(RH) * 4 + 0][3] = MF16(a0, vb3, acc[(RH) * 4 + 0][3]);            \
    acc[(RH) * 4 + 1][0] = MF16(a1, vb0, acc[(RH) * 4 + 1][0]);            \
    acc[(RH) * 4 + 1][1] = MF16(a1, vb1, acc[(RH) * 4 + 1][1]);            \
    acc[(RH) * 4 + 1][2] = MF16(a1, vb2, acc[(RH) * 4 + 1][2]);            \
    acc[(RH) * 4 + 1][3] = MF16(a1, vb3, acc[(RH) * 4 + 1][3]);            \
    acc[(RH) * 4 + 2][0] = MF16(a2, vb0, acc[(RH) * 4 + 2][0]);            \
    acc[(RH) * 4 + 2][1] = MF16(a2, vb1, acc[(RH) * 4 + 2][1]);            \
    acc[(RH) * 4 + 2][2] = MF16(a2, vb2, acc[(RH) * 4 + 2][2]);            \
    acc[(RH) * 4 + 2][3] = MF16(a2, vb3, acc[(RH) * 4 + 2][3]);            \
    acc[(RH) * 4 + 3][0] = MF16(a3, vb0, acc[(RH) * 4 + 3][0]);            \
    acc[(RH) * 4 + 3][1] = MF16(a3, vb1, acc[(RH) * 4 + 3][1]);            \
    acc[(RH) * 4 + 3][2] = MF16(a3, vb2, acc[(RH) * 4 + 3][2]);            \
    acc[(RH) * 4 + 3][3] = MF16(a3, vb3, acc[(RH) * 4 + 3][3]);            \
    __builtin_amdgcn_s_setprio(0);                                         \
    WAIT_STMT;                                                             \
    __builtin_amdgcn_sched_barrier(0);                                     \
    __builtin_amdgcn_s_barrier();                                          \
    __builtin_amdgcn_sched_barrier(0);                                     \
  }

#define TILE8(T, BUF)                                                        \
  PHASE(0, 0, BUF, 1, STAGE_A(1 - (BUF), 1, ((T) + 1) * 64 + 32), NOPS);     \
  PHASE(1, 0, BUF, 0, STAGE_B(1 - (BUF), 1, ((T) + 1) * 64 + 32), VMW(8));   \
  PHASE(0, 1, BUF, 1, STAGE_A(BUF, 0, ((T) + 2) * 64), NOPS);                \
  PHASE(1, 1, BUF, 0, STAGE_B(BUF, 0, ((T) + 2) * 64), VMW(8))

template <int EPI>
__global__ __launch_bounds__(512, 2) void gemm256(
    const short* __restrict__ A, int lda, long azk,
    const short* __restrict__ Bt, int ldb, long bzk,
    const float* __restrict__ bias, long biasl,
    void* __restrict__ outp, long czl, int ldc,
    void* __restrict__ aux, int K) {
  __shared__ __align__(16) short smem[65536];  // 128 KiB static

  const int t = threadIdx.x;
  const int wave = t >> 6, lane = t & 63;
  const int llo = lane & 15, lhi = lane >> 4;
  const int wm = wave >> 2, wn = wave & 3;

  // XCD-chunked bijective remap: keep x-partners (shared A panel) on one XCD
  int lin = blockIdx.x + gridDim.x * (blockIdx.y + gridDim.y * blockIdx.z);
  const int nwg = gridDim.x * gridDim.y * gridDim.z;  // % 8 == 0
  lin = (lin & 7) * (nwg >> 3) + (lin >> 3);
  const int bx = lin % gridDim.x;
  const int rem = lin / gridDim.x;
  const int by = rem % gridDim.y;
  const int z = rem / gridDim.y;

  const int bm0 = by * 256, bn0 = bx * 256;
  A += (long)z * azk;
  Bt += (long)z * bzk;

  // staging constants: thread loads rows (srow, srow+128), chunk pre-swizzled
  const int srow = t >> 2;                                 // 0..127
  const int sgc = (((t & 3) ^ ((t >> 3) & 3)) << 3);       // source chunk (shorts)
  const short* Ag  = A  + (long)(bm0 + srow) * lda + sgc;
  const short* Ag2 = A  + (long)(bm0 + 128 + srow) * lda + sgc;
  const short* Bg  = Bt + (long)(bn0 + srow) * ldb + sgc;
  const short* Bg2 = Bt + (long)(bn0 + 128 + srow) * ldb + sgc;
  const int wofs = wave * 512;                             // wave-uniform LDS base

  // fragment read constants (rows within region are multiples of 16 + llo)
  const int swz = ((lhi ^ ((llo >> 1) & 3)) << 3);
  const int aoff = (wm * 128 + llo) * 32 + swz;            // + RH*2048 + rt*512
  const int boff = (wn * 64 + llo) * 32 + swz;             // + ct*512

  f32x4 acc[8][4];
#pragma unroll
  for (int i = 0; i < 8; i++)
#pragma unroll
    for (int j = 0; j < 4; j++) acc[i][j] = f32x4{0.f, 0.f, 0.f, 0.f};
  bf16x8 vb0, vb1, vb2, vb3;  // B frags, loaded at RH=0, reused at RH=1

  const int NT = K >> 6;  // even, >= 4

  // prologue: tile0 (both K-halves) + tile1 K-half0; keep newest 8 in flight
  STAGE_A(0, 0, 0);  STAGE_B(0, 0, 0);
  STAGE_A(0, 1, 32); STAGE_B(0, 1, 32);
  STAGE_A(1, 0, 64); STAGE_B(1, 0, 64);
  VMW(8);
  __builtin_amdgcn_sched_barrier(0);
  __builtin_amdgcn_s_barrier();
  __builtin_amdgcn_sched_barrier(0);

  for (int tt = 0; tt < NT - 2; tt += 2) {
    TILE8(tt, 0);
    TILE8(tt + 1, 1);
  }
  // tail tile NT-2 (buf 0): stage only tile NT-1's K-half1
  PHASE(0, 0, 0, 1, STAGE_A(1, 1, (NT - 1) * 64 + 32), NOPS);
  PHASE(1, 0, 0, 0, STAGE_B(1, 1, (NT - 1) * 64 + 32), VMW(8));
  PHASE(0, 1, 0, 1, NOPS, NOPS);
  PHASE(1, 1, 0, 0, NOPS, VMW(4));
  // tail tile NT-1 (buf 1): no staging
  PHASE(0, 0, 1, 1, NOPS, NOPS);
  PHASE(1, 0, 1, 0, NOPS, VMW(0));
  PHASE(0, 1, 1, 1, NOPS, NOPS);
  PHASE(1, 1, 1, 0, NOPS, NOPS);

  if (EPI == E_PART) {
    // f32 partial, direct stores
    float* P = (float*)outp + (long)z * czl;
#pragma unroll
    for (int ct = 0; ct < 4; ct++) {
      const int col = bn0 + wn * 64 + ct * 16 + llo;
#pragma unroll
      for (int rt = 0; rt < 8; rt++) {
#pragma unroll
        for (int r = 0; r < 4; r++) {
          const int row = bm0 + wm * 128 + rt * 16 + lhi * 4 + r;
          P[(long)row * ldc + col] = acc[rt][ct][r];
        }
      }
    }
  } else if (EPI == E_QKV && z == 2) {
    // V8 projection: transposed write into V8T[bh][g][s] via per-wave slab
    short* slab = smem + wave * 4352;   // [64 cols][68] shorts
    const int bb = bm0 >> 10, sbase = (bm0 & 1023) + wm * 128;
    float bv4[4];
#pragma unroll
    for (int ct = 0; ct < 4; ct++)
      bv4[ct] = bias[z * biasl + bn0 + wn * 64 + ct * 16 + llo];
    const int gcol = bn0 + wn * 64 + lane;
    short* dst0 = (short*)aux + ((long)(bb * 8 + (gcol >> 7))) * 131072 +
                  (long)(gcol & 127) * 1024 + sbase;
#pragma unroll
    for (int p = 0; p < 2; p++) {
#pragma unroll
      for (int rt4 = 0; rt4 < 4; rt4++) {
#pragma unroll
        for (int ct = 0; ct < 4; ct++) {
#pragma unroll
          for (int r = 0; r < 4; r++) {
            float v = acc[p * 4 + rt4][ct][r] + bv4[ct];
            slab[(ct * 16 + llo) * 68 + rt4 * 16 + lhi * 4 + r] = f2bs(v);
          }
        }
      }
#pragma unroll
      for (int j = 0; j < 8; j++)
        *(short8*)(dst0 + p * 64 + j * 8) = *(const short8*)&slab[lane * 68 + j * 8];
    }
  } else {
    // bias (+GELU/+Qscale) -> bf16 via per-wave LDS slab -> short8 stores
    short* C = (short*)outp + (long)z * czl;
    short* slab = smem + wave * 4864;   // [64 rows][76 cols] shorts
    float bv4[4];
#pragma unroll
    for (int ct = 0; ct < 4; ct++)
      bv4[ct] = bias[z * biasl + bn0 + wn * 64 + ct * 16 + llo];
    const int rl0 = lane >> 3, cb8 = (lane & 7) << 3;
    const short* srd = slab + rl0 * 76 + cb8;
    short* Cw = C + (long)(bm0 + wm * 128 + rl0) * ldc + bn0 + wn * 64 + cb8;
#pragma unroll
    for (int p = 0; p < 2; p++) {
#pragma unroll
      for (int rt4 = 0; rt4 < 4; rt4++) {
#pragma unroll
        for (int ct = 0; ct < 4; ct++) {
#pragma unroll
          for (int r = 0; r < 4; r++) {
            float v = acc[p * 4 + rt4][ct][r] + bv4[ct];
            if (EPI == E_GELU)
              v = 0.5f * v * (1.0f + erff(v * 0.70710678118654752f));
            if (EPI == E_QKV && z == 0)
              v *= 0.12751744476582f;  // (1/sqrt(128)) * log2(e)
            slab[(rt4 * 16 + lhi * 4 + r) * 76 + ct * 16 + llo] = f2bs(v);
          }
        }
      }
#pragma unroll
      for (int j = 0; j < 8; j++) {
        short8 v = *(const short8*)(srd + j * 8 * 76);
        *(short8*)(Cw + ((long)p * 64 + j * 8) * ldc) = v;
      }
    }
  }
}

// ---------- launch ----------
extern "C" void kernel_launch(void* const* d_in, const int* in_sizes, int n_in,
                              void* d_out, int out_size, void* d_ws, size_t ws_size,
                              hipStream_t stream) {
  const float* x   = (const float*)d_in[0];
  // d_in[1] = mask (int32) — unused in infer path
  const float* g1  = (const float*)d_in[2];
  const float* b1  = (const float*)d_in[3];
  const float* Wq  = (const float*)d_in[4];
  const float* bq  = (const float*)d_in[5];
  const float* Wk  = (const float*)d_in[6];
  const float* bk  = (const float*)d_in[7];
  const float* Wv  = (const float*)d_in[8];
  const float* bv  = (const float*)d_in[9];
  const float* g2  = (const float*)d_in[10];
  const float* b2  = (const float*)d_in[11];
  const float* W1  = (const float*)d_in[12];
  const float* bw1 = (const float*)d_in[13];
  const float* W2  = (const float*)d_in[14];
  const float* bw2 = (const float*)d_in[15];

  char* ws = (char*)d_ws;
  const long MB = 1024 * 1024;
  // layout (peak 137MB; ws >= 189MB proven in round 5):
  float* bQKV  = (float*)(ws);            // [3][1024] f32: bq | bk | bv8
  float* x1    = (float*)(ws + 1 * MB);   // [4096,1024] f32  [1,17)
  short* wqT   = (short*)(ws + 17 * MB);  // [17,19)
  short* wkT   = (short*)(ws + 19 * MB);  // [19,21)  contiguous with wqT
  short* wv8T  = (short*)(ws + 21 * MB);  // [21,23)  contiguous (z*2MB)
  short* xn    = (short*)(ws + 23 * MB);  // [23,31)
  short* Q     = (short*)(ws + 31 * MB);  // [31,39)
  short* Kb    = (short*)(ws + 39 * MB);  // [39,47)  contiguous with Q
  short* V8T   = (short*)(ws + 47 * MB);  // [32][128][1024] bf16 [47,55)
  // FFN overlay (attention scratch dead by then):
  short* xn2  = (short*)(ws + 17 * MB);  // [17,25)
  short* Hb   = (short*)(ws + 25 * MB);  // [25,57)
  short* w1T  = (short*)(ws + 57 * MB);  // [57,65)
  short* w2T  = (short*)(ws + 65 * MB);  // [65,73)
  float* part = (float*)(ws + 73 * MB);  // [4][4096,1024] f32 [73,137)

  // fused prep: pair-pipelined transposes + wv8 + biases + LN1
  prep_k<<<5638, 256, 0, stream>>>(x, g1, b1, xn,
                                   Wq, wqT, Wk, wkT, Wv, wv8T,
                                   W1, w1T, W2, w2T,
                                   bq, bk, bv, bQKV);

  // QKV: z=0 -> Q (pre-scaled), z=1 -> Kb, z=2 -> V8T (transposed). K=1024.
  gemm256<E_QKV><<<dim3(4, 16, 3), 512, 0, stream>>>(
      xn, 1024, 0, wqT, 1024, 1048576, bQKV, 1024,
      Q, 4194304, 1024, V8T, 1024);

  // fused attention: scores+softmax+PV8+head-sum+residual -> x1
  flash_k<<<dim3(16, 32), 256, 0, stream>>>(Q, Kb, V8T, x, x1);

  // ---- FFN phase ----
  ln_k<<<4096, 256, 0, stream>>>(x1, g2, b2, xn2);

  // FFN1 + exact GELU -> Hb (bf16). K=1024.
  gemm256<E_GELU><<<dim3(16, 16, 1), 512, 0, stream>>>(
      xn2, 1024, 0, w1T, 1024, 0, bw1, 0,
      Hb, 0, 4096, nullptr, 1024);

  // FFN2 split-K=4: f32 partials (balanced; residual+bias in reduce4).
  gemm256<E_PART><<<dim3(4, 16, 4), 512, 0, stream>>>(
      Hb, 4096, 1024, w2T, 4096, 1024, nullptr, 0,
      part, 4194304, 1024, nullptr, 1024);

  reduce4_k<<<4096, 256, 0, stream>>>(part, x1, bw2, (float*)d_out);
}

// Round 12
// 334.747 us; speedup vs baseline: 1.1135x; 1.0399x over previous
//
#include <hip/hip_runtime.h>
#include <hip/hip_bf16.h>
#include <math.h>

// ---------- types ----------
typedef __attribute__((ext_vector_type(8))) short   short8;
typedef __attribute__((ext_vector_type(4))) short   short4v;
typedef __attribute__((ext_vector_type(8))) __bf16  bf16x8;
typedef __attribute__((ext_vector_type(4))) float   f32x4;

typedef const __attribute__((address_space(1))) void cgv_t;
typedef __attribute__((address_space(3))) void lv_t;

__device__ __forceinline__ float bs2f(short s) {
  unsigned int u = ((unsigned int)(unsigned short)s) << 16;
  return __builtin_bit_cast(float, u);
}
__device__ __forceinline__ short f2bs(float f) {
  __hip_bfloat16 h = __float2bfloat16(f);  // RNE
  return __builtin_bit_cast(short, h);
}
// async global->LDS, 16B per lane; lds base must be wave-uniform
__device__ __forceinline__ void glds16(const short* g, short* l) {
  __builtin_amdgcn_global_load_lds((cgv_t*)g, (lv_t*)l, 16, 0, 0);
}

// B=4, S=1024, D=1024, H=8, FF=4096, DK=128. I/O f32; internals bf16.
// Head-sum trick: attn[s,g] = sum_k P[s,k] * V8[k,g], V8 = xn @ Wv8,
// Wv8[:,r] = sum_{e<8} Wv[:,8r+e]. Attention fused flash-style.
// Q is pre-scaled by (1/sqrt(128))*log2(e) at the QKV epilogue, so the
// flash softmax runs entirely in the exp2 domain (raw v_exp_f32).
// Reference's raw reshape: (b,h,s,gg) attn value lands at x1 flat index
// ((b*8+h)*1024+s)*128+gg (verified round 6/8).

// ---------- prep device bodies ----------
// transpose unit descriptor: out[C][R] = bf16(in[R][C]), 64x64 tile (bx,by)
struct TrU { const float* in; short* out; int R, C, bx, by; };

__device__ __forceinline__ TrU tr_decode(
    int u,
    const float* Wq, short* wqT, const float* Wk, short* wkT,
    const float* W1, short* w1T, const float* W2, short* w2T) {
  TrU s;
  if (u < 1024)      { s.in = W1; s.out = w1T; s.R = 1024; s.C = 4096; s.bx = u & 63; s.by = u >> 6; }
  else if (u < 2048) { int v = u - 1024; s.in = W2; s.out = w2T; s.R = 4096; s.C = 1024; s.bx = v & 15; s.by = v >> 4; }
  else if (u < 2304) { int v = u - 2048; s.in = Wq; s.out = wqT; s.R = 1024; s.C = 1024; s.bx = v & 15; s.by = v >> 4; }
  else               { int v = u - 2304; s.in = Wk; s.out = wkT; s.R = 1024; s.C = 1024; s.bx = v & 15; s.by = v >> 4; }
  return s;
}

// pair-pipelined double transpose: all 8 global loads issued up-front,
// both LDS writes, ONE sync, both read+store phases.
__device__ __forceinline__ void tr2_body(const TrU& A, const TrU& B,
                                         short* T0, short* T1) {
  const int t = threadIdx.x;
  const int rr = t >> 4, cc = (t & 15) << 2;
  f32x4 va[4], vb[4];
#pragma unroll
  for (int h = 0; h < 4; h++)
    va[h] = *(const f32x4*)(A.in + (long)(A.by * 64 + rr + h * 16) * A.C + A.bx * 64 + cc);
#pragma unroll
  for (int h = 0; h < 4; h++)
    vb[h] = *(const f32x4*)(B.in + (long)(B.by * 64 + rr + h * 16) * B.C + B.bx * 64 + cc);
#pragma unroll
  for (int h = 0; h < 4; h++)
#pragma unroll
    for (int e = 0; e < 4; e++) {
      T0[(rr + h * 16) * 72 + cc + e] = f2bs(va[h][e]);
      T1[(rr + h * 16) * 72 + cc + e] = f2bs(vb[h][e]);
    }
  __syncthreads();
  const int cr = t >> 3, rs = (t & 7) << 3;
#pragma unroll
  for (int hf = 0; hf < 2; hf++) {
    const int c = cr + hf * 32;
    short8 v0, v1;
#pragma unroll
    for (int e = 0; e < 8; e++) { v0[e] = T0[(rs + e) * 72 + c]; v1[e] = T1[(rs + e) * 72 + c]; }
    *(short8*)(A.out + (long)(A.bx * 64 + c) * A.R + A.by * 64 + rs) = v0;
    *(short8*)(B.out + (long)(B.bx * 64 + c) * B.R + B.by * 64 + rs) = v1;
  }
}

// wv8T[r][k] = bf16( sum_{e<8} Wv[k][8r+e] ); 64x64 tile
__device__ __forceinline__ void wv8_body(const float* __restrict__ Wv,
                                         short* __restrict__ out,
                                         int bx, int by, short* T) {
  const int r0 = bx * 64, k0 = by * 64;
  const int t = threadIdx.x;
  const int wave = t >> 6, lane = t & 63;
  const int r = r0 + lane;
#pragma unroll 4
  for (int i = 0; i < 16; i++) {
    const int k = k0 + wave * 16 + i;
    const float* src = Wv + (long)k * 8192 + 8 * r;
    f32x4 a = *(const f32x4*)src;
    f32x4 b = *(const f32x4*)(src + 4);
    float s = (a[0] + a[1] + a[2] + a[3]) + (b[0] + b[1] + b[2] + b[3]);
    T[lane * 72 + wave * 16 + i] = f2bs(s);
  }
  __syncthreads();
  const int rr = t >> 3, kc = (t & 7) << 3;
#pragma unroll
  for (int half = 0; half < 2; half++) {
    const int rl = rr + half * 32;
    *(short8*)(out + (long)(r0 + rl) * 1024 + k0 + kc) = *(const short8*)&T[rl * 72 + kc];
  }
}

// layernorm row of 1024; f32 in/params; bf16 out
__device__ __forceinline__ void ln_body(const float* __restrict__ in,
                                        const float* __restrict__ g,
                                        const float* __restrict__ b,
                                        short* __restrict__ out, int row,
                                        float* rs, float* rq) {
  const int t = threadIdx.x;
  const long base = (long)row * 1024 + t * 4;
  f32x4 f = *(const f32x4*)(in + base);
  float v[4] = {f[0], f[1], f[2], f[3]};
  float s1 = v[0] + v[1] + v[2] + v[3];
  float s2 = v[0]*v[0] + v[1]*v[1] + v[2]*v[2] + v[3]*v[3];
#pragma unroll
  for (int off = 32; off; off >>= 1) {
    s1 += __shfl_xor(s1, off);
    s2 += __shfl_xor(s2, off);
  }
  if ((t & 63) == 0) { rs[t >> 6] = s1; rq[t >> 6] = s2; }
  __syncthreads();
  s1 = rs[0] + rs[1] + rs[2] + rs[3];
  s2 = rq[0] + rq[1] + rq[2] + rq[3];
  const float mean = s1 * (1.0f / 1024.0f);
  const float var  = s2 * (1.0f / 1024.0f) - mean * mean;
  const float rstd = rsqrtf(var + 1e-5f);
  f32x4 gv = *(const f32x4*)(g + t * 4);
  f32x4 bv = *(const f32x4*)(b + t * 4);
  short4v o;
#pragma unroll
  for (int i = 0; i < 4; i++)
    o[i] = f2bs((v[i] - mean) * rstd * gv[i] + bv[i]);
  *(short4v*)(out + base) = o;
}

// ---------- fused prep ----------
// [0,1280): tr pairs (units 2b, 2b+1 of 2560: W1|W2|Wq|Wk)
// [1280,1536): wv8 tiles | [1536,1540): bv8 | 1540,1541: bq/bk copy
// [1542, 5638): LN1 rows. Total 5638 blocks.
__global__ __launch_bounds__(256) void prep_k(
    const float* __restrict__ x, const float* __restrict__ g1,
    const float* __restrict__ b1, short* __restrict__ xn,
    const float* __restrict__ Wq, short* __restrict__ wqT,
    const float* __restrict__ Wk, short* __restrict__ wkT,
    const float* __restrict__ Wv, short* __restrict__ wv8T,
    const float* __restrict__ W1, short* __restrict__ w1T,
    const float* __restrict__ W2, short* __restrict__ w2T,
    const float* __restrict__ bq, const float* __restrict__ bk,
    const float* __restrict__ bv, float* __restrict__ bQKV) {
  __shared__ __align__(16) short T[2][64 * 72];
  __shared__ float rs[4], rq[4];
  const int t = threadIdx.x;
  int bid = blockIdx.x;
  if (bid < 1280) {
    TrU A = tr_decode(bid * 2,     Wq, wqT, Wk, wkT, W1, w1T, W2, w2T);
    TrU B = tr_decode(bid * 2 + 1, Wq, wqT, Wk, wkT, W1, w1T, W2, w2T);
    tr2_body(A, B, T[0], T[1]);
    return;
  }
  bid -= 1280;
  if (bid < 256) { wv8_body(Wv, wv8T, bid & 15, bid >> 4, T[0]); return; }
  bid -= 256;
  if (bid < 4) {
    const int r = bid * 256 + t;
    f32x4 a = *(const f32x4*)(bv + 8 * r);
    f32x4 b = *(const f32x4*)(bv + 8 * r + 4);
    bQKV[2048 + r] = (a[0] + a[1] + a[2] + a[3]) + (b[0] + b[1] + b[2] + b[3]);
    return;
  }
  bid -= 4;
  if (bid == 0) { *(f32x4*)(bQKV + t * 4) = *(const f32x4*)(bq + t * 4); return; }
  if (bid == 1) { *(f32x4*)(bQKV + 1024 + t * 4) = *(const f32x4*)(bk + t * 4); return; }
  ln_body(x, g1, b1, xn, bid - 2, rs, rq);
}

// ---------- layernorm kernel (2nd LN: x1 -> xn2) ----------
__global__ __launch_bounds__(256) void ln_k(const float* __restrict__ in,
                                            const float* __restrict__ g,
                                            const float* __restrict__ b,
                                            short* __restrict__ out) {
  __shared__ float rs[4], rq[4];
  ln_body(in, g, b, out, blockIdx.x, rs, rq);
}

// ---------- split-K=4 reduce: d_out = p0..p3 + x1 + bias ----------
__global__ __launch_bounds__(256) void reduce4_k(const float* __restrict__ p,
                                                 const float* __restrict__ x1,
                                                 const float* __restrict__ bias,
                                                 float* __restrict__ out) {
  const int t = threadIdx.x;
  const long base = (long)blockIdx.x * 1024 + t * 4;
  f32x4 a = *(const f32x4*)(p + base);
  f32x4 b = *(const f32x4*)(p + 4194304 + base);
  f32x4 c = *(const f32x4*)(p + 8388608 + base);
  f32x4 d = *(const f32x4*)(p + 12582912 + base);
  f32x4 e = *(const f32x4*)(x1 + base);
  f32x4 g = *(const f32x4*)(bias + t * 4);
  *(f32x4*)(out + base) = a + b + c + d + e + g;
}

// ---------- fused flash attention (+head-sum + residual) ----------
// Q pre-scaled by SC*log2e; softmax in exp2 domain; defer-max (THR=8,
// exact: m cancels in o/l). XCD swizzle: XCD r owns bh in [4r,4r+4) so
// its K/V working set (2MB) is L2-resident. T2 XOR swizzle on LDS slabs.
__global__ __launch_bounds__(256, 2) void flash_k(
    const short* __restrict__ Qg_, const short* __restrict__ Kg_,
    const short* __restrict__ V8T, const float* __restrict__ xg,
    float* __restrict__ x1) {
  __shared__ __align__(16) short smem[40960];  // 80 KB exactly
  short* Qs = smem;            // 4 * [64][32]  (slab 2048 shorts)
  short* Ks = smem + 8192;     // 4 * [128][32] (slab 4096); P reuses rows 0..63
  short* Vs = smem + 24576;    // 4 * [128][32]

  const int t = threadIdx.x;
  const int wave = t >> 6, lane = t & 63;
  const int llo = lane & 15, lhi = lane >> 4;

  // XCD-grouped remap: 512 blocks, XCD r <- bh in [4r, 4r+4), all 16 q-tiles
  int lin = blockIdx.x + (blockIdx.y << 4);
  lin = (lin & 7) * 64 + (lin >> 3);
  const int q0 = (lin & 15) * 64;
  const int bh = lin >> 4, b = bh >> 3, h = bh & 7;

  const short* Qg = Qg_ + ((long)(b * 1024 + q0)) * 1024 + h * 128;
  const short* Kg = Kg_ + ((long)b * 1024) * 1024 + h * 128;
  const short* Vg = V8T + (long)bh * 131072;   // [128 g][1024 s]

  const int srow = t >> 2;
  const int sgc = (((t & 3) ^ ((t >> 3) & 3)) << 3);  // pre-swizzled src chunk
  const int wbase = wave * 512;          // wave-uniform stage base (shorts)
  const int swzo = ((lhi ^ ((llo >> 1) & 3)) << 3);   // swizzled frag chunk
  const int arow = (wave * 16 + llo) * 32 + swzo;     // Q / P frag read

#pragma unroll
  for (int kk = 0; kk < 4; kk++)
    glds16(Qg + (long)srow * 1024 + kk * 32 + sgc, Qs + kk * 2048 + wbase);

  f32x4 o[8];
  float mR[4], lR[4];
#pragma unroll
  for (int i = 0; i < 8; i++) o[i] = f32x4{0.f, 0.f, 0.f, 0.f};
#pragma unroll
  for (int r = 0; r < 4; r++) { mR[r] = -1e30f; lR[r] = 0.f; }

  for (int it = 0; it < 8; it++) {
    const int kt0 = it * 128;
#pragma unroll
    for (int kk = 0; kk < 4; kk++) {
      glds16(Kg + (long)(kt0 + srow) * 1024 + kk * 32 + sgc,
             Ks + kk * 4096 + wbase);
      glds16(Kg + (long)(kt0 + 64 + srow) * 1024 + kk * 32 + sgc,
             Ks + kk * 4096 + 2048 + wbase);
      glds16(Vg + (long)srow * 1024 + kt0 + kk * 32 + sgc,
             Vs + kk * 4096 + wbase);
      glds16(Vg + (long)(64 + srow) * 1024 + kt0 + kk * 32 + sgc,
             Vs + kk * 4096 + 2048 + wbase);
    }
    __syncthreads();

    f32x4 s[8];
#pragma unroll
    for (int i = 0; i < 8; i++) s[i] = f32x4{0.f, 0.f, 0.f, 0.f};
#pragma unroll
    for (int kk = 0; kk < 4; kk++) {
      bf16x8 aq = *(const bf16x8*)(Qs + kk * 2048 + arow);
#pragma unroll
      for (int ct = 0; ct < 8; ct++) {
        bf16x8 bk = *(const bf16x8*)(Ks + kk * 4096 + (ct * 16 + llo) * 32 + swzo);
        s[ct] = __builtin_amdgcn_mfma_f32_16x16x32_bf16(aq, bk, s[ct], 0, 0, 0);
      }
    }
    // scores already scaled by SC*log2e (folded into Q); exp2 domain
    float mt[4];
#pragma unroll
    for (int r = 0; r < 4; r++) {
      float m = s[0][r];
#pragma unroll
      for (int ct = 1; ct < 8; ct++) m = fmaxf(m, s[ct][r]);
      m = fmaxf(m, __shfl_xor(m, 1));
      m = fmaxf(m, __shfl_xor(m, 2));
      m = fmaxf(m, __shfl_xor(m, 4));
      m = fmaxf(m, __shfl_xor(m, 8));
      mt[r] = m;
    }
    // defer-max: only rescale when max grew by > 8 (P bounded by 2^8)
    bool need = (mt[0] > mR[0] + 8.f) | (mt[1] > mR[1] + 8.f) |
                (mt[2] > mR[2] + 8.f) | (mt[3] > mR[3] + 8.f);
    if (__any(need)) {
      float alpha[4];
#pragma unroll
      for (int r = 0; r < 4; r++) {
        const float mn = fmaxf(mR[r], mt[r]);
        alpha[r] = __builtin_amdgcn_exp2f(mR[r] - mn);
        mR[r] = mn;
        lR[r] *= alpha[r];
      }
#pragma unroll
      for (int ct = 0; ct < 8; ct++)
#pragma unroll
        for (int r = 0; r < 4; r++) o[ct][r] *= alpha[r];
    }
#pragma unroll
    for (int ct = 0; ct < 8; ct++)
#pragma unroll
      for (int r = 0; r < 4; r++)
        s[ct][r] = __builtin_amdgcn_exp2f(s[ct][r] - mR[r]);
#pragma unroll
    for (int r = 0; r < 4; r++) {
      float ls = s[0][r];
#pragma unroll
      for (int ct = 1; ct < 8; ct++) ls += s[ct][r];
      ls += __shfl_xor(ls, 1);
      ls += __shfl_xor(ls, 2);
      ls += __shfl_xor(ls, 4);
      ls += __shfl_xor(ls, 8);
      lR[r] += ls;
    }
    __syncthreads();

    // P -> Ks rows 0..63, swizzled slots (col' matches swizzled P-read)
#pragma unroll
    for (int ct = 0; ct < 8; ct++) {
      const int chunk = ((ct & 1) << 1) | (llo >> 3);
      const int cl = llo & 7;
#pragma unroll
      for (int r = 0; r < 4; r++) {
        const int row = wave * 16 + lhi * 4 + r;
        const int xr = ((lhi << 1) | (r >> 1)) & 3;
        Ks[(ct >> 1) * 4096 + row * 32 + (((chunk ^ xr) << 3) | cl)] = f2bs(s[ct][r]);
      }
    }
    __syncthreads();

#pragma unroll
    for (int kk = 0; kk < 4; kk++) {
      bf16x8 ap = *(const bf16x8*)(Ks + kk * 4096 + arow);
#pragma unroll
      for (int ct = 0; ct < 8; ct++) {
        bf16x8 bv = *(const bf16x8*)(Vs + kk * 4096 + (ct * 16 + llo) * 32 + swzo);
        o[ct] = __builtin_amdgcn_mfma_f32_16x16x32_bf16(ap, bv, o[ct], 0, 0, 0);
      }
    }
    __syncthreads();
  }

  float inv[4];
#pragma unroll
  for (int r = 0; r < 4; r++) inv[r] = 1.0f / lR[r];
#pragma unroll
  for (int ct = 0; ct < 8; ct++) {
#pragma unroll
    for (int r = 0; r < 4; r++) {
      const int row = q0 + wave * 16 + lhi * 4 + r;
      const long idx = ((long)(b * 8 + h) * 1024 + row) * 128 + ct * 16 + llo;
      x1[idx] = xg[idx] + o[ct][r] * inv[r];
    }
  }
}

// ======================================================================
// 256x256 8-phase bf16 GEMM (T1 XCD swizzle + T2 swizzle + T3/T4 counted
// vmcnt + T5 setprio). 512 thr = 8 waves (2M x 4N), per-wave out 128x64,
// BK=64 (2 K-halves). LDS 128 KiB STATIC. One trailing barrier per phase.
// Epilogues: E_QKV (bias->bf16; z==0 scaled by SC*log2e; z==2 ->
// transposed write into V8T head layout via aux), E_PART (f32 partial).
// Per-z offsets: A += z*azk, Bt += z*bzk (shorts), bias += z*biasl.
// Requires NT=K/64 even, >=4; grid blocks %8 == 0.
// ======================================================================
enum { E_GELU = 0, E_QKV = 1, E_PART = 2 };

#define MF16(va, vb, vc) __builtin_amdgcn_mfma_f32_16x16x32_bf16(va, vb, vc, 0, 0, 0)
#define VMW(n) asm volatile("s_waitcnt vmcnt(" #n ")" ::: "memory")
#define NOPS ((void)0)

#define STAGE_A(BUF, KH, KB) do {                                          \
    glds16(Ag + (KB), smem + ((BUF) * 2 + (KH)) * 8192 + wofs);            \
    glds16(Ag2 + (KB), smem + ((BUF) * 2 + (KH)) * 8192 + 4096 + wofs);    \
  } while (0)
#define STAGE_B(BUF, KH, KB) do {                                          \
    glds16(Bg + (KB), smem + 32768 + ((BUF) * 2 + (KH)) * 8192 + wofs);    \
    glds16(Bg2 + (KB), smem + 32768 + ((BUF) * 2 + (KH)) * 8192 + 4096 + wofs); \
  } while (0)

// LOADB=1 -> load vb0..vb3 (B frags) this phase; LOADB=0 -> reuse.
#define PHASE(RH, KH, BUF, LOADB, STAGE_STMT, WAIT_STMT)                   \
  {                                                                        \
    const short* Ar_ = smem + ((BUF) * 2 + (KH)) * 8192 + aoff + (RH) * 2048; \
    bf16x8 a0 = *(const bf16x8*)(Ar_);                                     \
    bf16x8 a1 = *(const bf16x8*)(Ar_ + 512);                               \
    bf16x8 a2 = *(const bf16x8*)(Ar_ + 1024);                              \
    bf16x8 a3 = *(const bf16x8*)(Ar_ + 1536);                              \
    if (LOADB) {                                                           \
      const short* Br_ = smem + 32768 + ((BUF) * 2 + (KH)) * 8192 + boff;  \
      vb0 = *(const bf16x8*)(Br_);                                         \
      vb1 = *(const bf16x8*)(Br_ + 512);                                   \
      vb2 = *(const bf16x8*)(Br_ + 1024);                                  \
      vb3 = *(const bf16x8*)(Br_ + 1536);                                  \
    }                                                                      \
    STAGE_STMT;                                                            \
    __builtin_amdgcn_s_setprio(1);                                         \
    acc[(RH) * 4 + 0][0] = MF16(a0, vb0, acc[(RH) * 4 + 0][0]);            \
    acc[(RH) * 4 + 0][1] = MF16(a0, vb1, acc[(RH) * 4 + 0][1]);            \
    acc[(RH) * 4 + 0][2] = MF16(a0, vb2, acc[(RH) * 4 + 0][2]);            \
    acc[(RH) * 4 + 0][3] = MF16(a0, vb3, acc[(RH) * 4 + 0][3]);            \
    acc[(RH) * 4 + 1][0] = MF16(a1, vb0, acc[(RH) * 4 + 1][0]);            \
    acc[(RH) * 4 + 1][1] = MF16(a1, vb1, acc[(RH) * 4 + 1][1]);            \
    acc[(RH) * 4 + 1][2] = MF16(a1, vb2, acc[(RH) * 4 + 1][2]);            \
    acc[(RH) * 4 + 1][3] = MF16(a1, vb3, acc[(RH) * 4 + 1][3]);            \
    acc[(RH) * 4 + 2][0] = MF16(a2, vb0, acc[(RH) * 4 + 2][0]);            \
    acc[(RH) * 4 + 2][1] = MF16(a2, vb1, acc[(RH) * 4 + 2][1]);            \
    acc[(RH) * 4 + 2][2] = MF16(a2, vb2, acc[(RH) * 4 + 2][2]);            \
    acc[(RH) * 4 + 2][3] = MF16(a2, vb3, acc[(RH) * 4 + 2][3]);            \
    acc[(RH) * 4 + 3][0] = MF16(a3, vb0, acc[(RH) * 4 + 3][0]);            \
    acc[(RH) * 4 + 3][1] = MF16(a3, vb1, acc[(RH) * 4 + 3][1]);            \
    acc[(RH) * 4 + 3][2] = MF16(a3, vb2, acc[(RH) * 4 + 3][2]);            \
    acc[(RH) * 4 + 3][3] = MF16(a3, vb3, acc[(RH) * 4 + 3][3]);            \
    __builtin_amdgcn_s_setprio(0);                                         \
    WAIT_STMT;                                                             \
    __builtin_amdgcn_sched_barrier(0);                                     \
    __builtin_amdgcn_s_barrier();                                          \
    __builtin_amdgcn_sched_barrier(0);                                     \
  }

#define TILE8(T, BUF)                                                        \
  PHASE(0, 0, BUF, 1, STAGE_A(1 - (BUF), 1, ((T) + 1) * 64 + 32), NOPS);     \
  PHASE(1, 0, BUF, 0, STAGE_B(1 - (BUF), 1, ((T) + 1) * 64 + 32), VMW(8));   \
  PHASE(0, 1, BUF, 1, STAGE_A(BUF, 0, ((T) + 2) * 64), NOPS);                \
  PHASE(1, 1, BUF, 0, STAGE_B(BUF, 0, ((T) + 2) * 64), VMW(8))

template <int EPI>
__global__ __launch_bounds__(512, 2) void gemm256(
    const short* __restrict__ A, int lda, long azk,
    const short* __restrict__ Bt, int ldb, long bzk,
    const float* __restrict__ bias, long biasl,
    void* __restrict__ outp, long czl, int ldc,
    void* __restrict__ aux, int K) {
  __shared__ __align__(16) short smem[65536];  // 128 KiB static

  const int t = threadIdx.x;
  const int wave = t >> 6, lane = t & 63;
  const int llo = lane & 15, lhi = lane >> 4;
  const int wm = wave >> 2, wn = wave & 3;

  // XCD-chunked bijective remap: keep x-partners (shared A panel) on one XCD
  int lin = blockIdx.x + gridDim.x * (blockIdx.y + gridDim.y * blockIdx.z);
  const int nwg = gridDim.x * gridDim.y * gridDim.z;  // % 8 == 0
  lin = (lin & 7) * (nwg >> 3) + (lin >> 3);
  const int bx = lin % gridDim.x;
  const int rem = lin / gridDim.x;
  const int by = rem % gridDim.y;
  const int z = rem / gridDim.y;

  const int bm0 = by * 256, bn0 = bx * 256;
  A += (long)z * azk;
  Bt += (long)z * bzk;

  // staging constants: thread loads rows (srow, srow+128), chunk pre-swizzled
  const int srow = t >> 2;                                 // 0..127
  const int sgc = (((t & 3) ^ ((t >> 3) & 3)) << 3);       // source chunk (shorts)
  const short* Ag  = A  + (long)(bm0 + srow) * lda + sgc;
  const short* Ag2 = A  + (long)(bm0 + 128 + srow) * lda + sgc;
  const short* Bg  = Bt + (long)(bn0 + srow) * ldb + sgc;
  const short* Bg2 = Bt + (long)(bn0 + 128 + srow) * ldb + sgc;
  const int wofs = wave * 512;                             // wave-uniform LDS base

  // fragment read constants (rows within region are multiples of 16 + llo)
  const int swz = ((lhi ^ ((llo >> 1) & 3)) << 3);
  const int aoff = (wm * 128 + llo) * 32 + swz;            // + RH*2048 + rt*512
  const int boff = (wn * 64 + llo) * 32 + swz;             // + ct*512

  f32x4 acc[8][4];
#pragma unroll
  for (int i = 0; i < 8; i++)
#pragma unroll
    for (int j = 0; j < 4; j++) acc[i][j] = f32x4{0.f, 0.f, 0.f, 0.f};
  bf16x8 vb0, vb1, vb2, vb3;  // B frags, loaded at RH=0, reused at RH=1

  const int NT = K >> 6;  // even, >= 4

  // prologue: tile0 (both K-halves) + tile1 K-half0; keep newest 8 in flight
  STAGE_A(0, 0, 0);  STAGE_B(0, 0, 0);
  STAGE_A(0, 1, 32); STAGE_B(0, 1, 32);
  STAGE_A(1, 0, 64); STAGE_B(1, 0, 64);
  VMW(8);
  __builtin_amdgcn_sched_barrier(0);
  __builtin_amdgcn_s_barrier();
  __builtin_amdgcn_sched_barrier(0);

  for (int tt = 0; tt < NT - 2; tt += 2) {
    TILE8(tt, 0);
    TILE8(tt + 1, 1);
  }
  // tail tile NT-2 (buf 0): stage only tile NT-1's K-half1
  PHASE(0, 0, 0, 1, STAGE_A(1, 1, (NT - 1) * 64 + 32), NOPS);
  PHASE(1, 0, 0, 0, STAGE_B(1, 1, (NT - 1) * 64 + 32), VMW(8));
  PHASE(0, 1, 0, 1, NOPS, NOPS);
  PHASE(1, 1, 0, 0, NOPS, VMW(4));
  // tail tile NT-1 (buf 1): no staging
  PHASE(0, 0, 1, 1, NOPS, NOPS);
  PHASE(1, 0, 1, 0, NOPS, VMW(0));
  PHASE(0, 1, 1, 1, NOPS, NOPS);
  PHASE(1, 1, 1, 0, NOPS, NOPS);

  if (EPI == E_PART) {
    // f32 partial, direct stores
    float* P = (float*)outp + (long)z * czl;
#pragma unroll
    for (int ct = 0; ct < 4; ct++) {
      const int col = bn0 + wn * 64 + ct * 16 + llo;
#pragma unroll
      for (int rt = 0; rt < 8; rt++) {
#pragma unroll
        for (int r = 0; r < 4; r++) {
          const int row = bm0 + wm * 128 + rt * 16 + lhi * 4 + r;
          P[(long)row * ldc + col] = acc[rt][ct][r];
        }
      }
    }
  } else if (EPI == E_QKV && z == 2) {
    // V8 projection: transposed write into V8T[bh][g][s] via per-wave slab
    short* slab = smem + wave * 4352;   // [64 cols][68] shorts
    const int bb = bm0 >> 10, sbase = (bm0 & 1023) + wm * 128;
    float bv4[4];
#pragma unroll
    for (int ct = 0; ct < 4; ct++)
      bv4[ct] = bias[z * biasl + bn0 + wn * 64 + ct * 16 + llo];
    const int gcol = bn0 + wn * 64 + lane;
    short* dst0 = (short*)aux + ((long)(bb * 8 + (gcol >> 7))) * 131072 +
                  (long)(gcol & 127) * 1024 + sbase;
#pragma unroll
    for (int p = 0; p < 2; p++) {
#pragma unroll
      for (int rt4 = 0; rt4 < 4; rt4++) {
#pragma unroll
        for (int ct = 0; ct < 4; ct++) {
#pragma unroll
          for (int r = 0; r < 4; r++) {
            float v = acc[p * 4 + rt4][ct][r] + bv4[ct];
            slab[(ct * 16 + llo) * 68 + rt4 * 16 + lhi * 4 + r] = f2bs(v);
          }
        }
      }
#pragma unroll
      for (int j = 0; j < 8; j++)
        *(short8*)(dst0 + p * 64 + j * 8) = *(const short8*)&slab[lane * 68 + j * 8];
    }
  } else {
    // bias (+Qscale) -> bf16 via per-wave LDS slab -> short8 stores
    short* C = (short*)outp + (long)z * czl;
    short* slab = smem + wave * 4864;   // [64 rows][76 cols] shorts
    float bv4[4];
#pragma unroll
    for (int ct = 0; ct < 4; ct++)
      bv4[ct] = bias[z * biasl + bn0 + wn * 64 + ct * 16 + llo];
    const int rl0 = lane >> 3, cb8 = (lane & 7) << 3;
    const short* srd = slab + rl0 * 76 + cb8;
    short* Cw = C + (long)(bm0 + wm * 128 + rl0) * ldc + bn0 + wn * 64 + cb8;
#pragma unroll
    for (int p = 0; p < 2; p++) {
#pragma unroll
      for (int rt4 = 0; rt4 < 4; rt4++) {
#pragma unroll
        for (int ct = 0; ct < 4; ct++) {
#pragma unroll
          for (int r = 0; r < 4; r++) {
            float v = acc[p * 4 + rt4][ct][r] + bv4[ct];
            if (EPI == E_QKV && z == 0)
              v *= 0.12751744476582f;  // (1/sqrt(128)) * log2(e)
            slab[(rt4 * 16 + lhi * 4 + r) * 76 + ct * 16 + llo] = f2bs(v);
          }
        }
      }
#pragma unroll
      for (int j = 0; j < 8; j++) {
        short8 v = *(const short8*)(srd + j * 8 * 76);
        *(short8*)(Cw + ((long)p * 64 + j * 8) * ldc) = v;
      }
    }
  }
}

// ======================================================================
// FFN1: 128x256 bf16 GEMM + GELU, 2 blocks/CU (cross-block overlap).
// 512 thr = 8 waves (2M x 4N), per-wave out 64x64 (acc 4x4 f32x4 = 64 AGPR).
// BK=32 classic double-buffer, counted vmcnt(3) (never 0 in loop).
// LDS: staging 2 bufs x (A[128][32] + B[256][32]) = 24576 shorts;
// epilogue slabs 8 x [64][76] = 38912 shorts -> block LDS 77824 B -> 2/CU.
// T2 swizzle identical to gemm256 (pre-swizzled source + swizzled reads).
// Body: {ds_read frags; MFMA; barrier; stage i+2 into cur; VMW; barrier}.
// Grid (16,32) = 512 blocks = 2/CU; XCD-chunked remap.
// ======================================================================
__global__ __launch_bounds__(512, 4) void gemm128n_gelu(
    const short* __restrict__ A, int lda,
    const short* __restrict__ Bt, int ldb,
    const float* __restrict__ bias,
    short* __restrict__ C, int ldc, int K) {
  __shared__ __align__(16) short smem[38912];

  const int t = threadIdx.x;
  const int wave = t >> 6, lane = t & 63;
  const int llo = lane & 15, lhi = lane >> 4;
  const int wm = wave >> 2, wn = wave & 3;

  int lin = blockIdx.x + (blockIdx.y << 4);  // gridDim = (16,32)
  lin = (lin & 7) * 64 + (lin >> 3);
  const int bn0 = (lin & 15) * 256;
  const int bm0 = (lin >> 4) * 128;

  const int srow = t >> 2;
  const int sgc = (((t & 3) ^ ((t >> 3) & 3)) << 3);
  const short* Ag  = A  + (long)(bm0 + srow) * lda + sgc;
  const short* Bg  = Bt + (long)(bn0 + srow) * ldb + sgc;
  const short* Bg2 = Bt + (long)(bn0 + 128 + srow) * ldb + sgc;
  const int wofs = wave * 512;

  const int swz = ((lhi ^ ((llo >> 1) & 3)) << 3);
  const int aoff = (wm * 64 + llo) * 32 + swz;   // + rt*512 within A region
  const int boff = (wn * 64 + llo) * 32 + swz;   // + ct*512 within B region

  f32x4 acc[4][4];
#pragma unroll
  for (int i = 0; i < 4; i++)
#pragma unroll
    for (int j = 0; j < 4; j++) acc[i][j] = f32x4{0.f, 0.f, 0.f, 0.f};

#define STG(BUF, KB) do {                                                  \
    glds16(Ag + (KB), smem + (BUF) * 12288 + wofs);                        \
    glds16(Bg + (KB), smem + (BUF) * 12288 + 4096 + wofs);                 \
    glds16(Bg2 + (KB), smem + (BUF) * 12288 + 8192 + wofs);                \
  } while (0)

#define BODY(BUF, STAGE_STMT, WAIT_STMT)                                   \
  {                                                                        \
    const short* Ab_ = smem + (BUF) * 12288 + aoff;                        \
    const short* Bb_ = smem + (BUF) * 12288 + 4096 + boff;                 \
    bf16x8 a0 = *(const bf16x8*)(Ab_);                                     \
    bf16x8 a1 = *(const bf16x8*)(Ab_ + 512);                               \
    bf16x8 a2 = *(const bf16x8*)(Ab_ + 1024);                              \
    bf16x8 a3 = *(const bf16x8*)(Ab_ + 1536);                              \
    bf16x8 b0 = *(const bf16x8*)(Bb_);                                     \
    bf16x8 b1 = *(const bf16x8*)(Bb_ + 512);                               \
    bf16x8 b2 = *(const bf16x8*)(Bb_ + 1024);                              \
    bf16x8 b3 = *(const bf16x8*)(Bb_ + 1536);                              \
    __builtin_amdgcn_s_setprio(1);                                         \
    acc[0][0] = MF16(a0, b0, acc[0][0]); acc[0][1] = MF16(a0, b1, acc[0][1]); \
    acc[0][2] = MF16(a0, b2, acc[0][2]); acc[0][3] = MF16(a0, b3, acc[0][3]); \
    acc[1][0] = MF16(a1, b0, acc[1][0]); acc[1][1] = MF16(a1, b1, acc[1][1]); \
    acc[1][2] = MF16(a1, b2, acc[1][2]); acc[1][3] = MF16(a1, b3, acc[1][3]); \
    acc[2][0] = MF16(a2, b0, acc[2][0]); acc[2][1] = MF16(a2, b1, acc[2][1]); \
    acc[2][2] = MF16(a2, b2, acc[2][2]); acc[2][3] = MF16(a2, b3, acc[2][3]); \
    acc[3][0] = MF16(a3, b0, acc[3][0]); acc[3][1] = MF16(a3, b1, acc[3][1]); \
    acc[3][2] = MF16(a3, b2, acc[3][2]); acc[3][3] = MF16(a3, b3, acc[3][3]); \
    __builtin_amdgcn_s_setprio(0);                                         \
    __builtin_amdgcn_sched_barrier(0);                                     \
    __builtin_amdgcn_s_barrier();                                          \
    __builtin_amdgcn_sched_barrier(0);                                     \
    STAGE_STMT;                                                            \
    WAIT_STMT;                                                             \
    __builtin_amdgcn_sched_barrier(0);                                     \
    __builtin_amdgcn_s_barrier();                                          \
    __builtin_amdgcn_sched_barrier(0);                                     \
  }

  const int NT = K >> 5;  // 32 for K=1024; even, >= 4

  // prologue: stage first two K-steps; wait for step0 (3 newest in flight)
  STG(0, 0);
  STG(1, 32);
  VMW(3);
  __builtin_amdgcn_sched_barrier(0);
  __builtin_amdgcn_s_barrier();
  __builtin_amdgcn_sched_barrier(0);

  for (int i = 0; i < NT - 2; i += 2) {
    BODY(0, STG(0, (i + 2) * 32), VMW(3));
    BODY(1, STG(1, (i + 3) * 32), VMW(3));
  }
  BODY(0, NOPS, VMW(0));
  BODY(1, NOPS, NOPS);

  // epilogue: bias + exact GELU -> per-wave slab [64][76] -> short8 stores
  short* slab = smem + wave * 4864;
  float bv4[4];
#pragma unroll
  for (int ct = 0; ct < 4; ct++) bv4[ct] = bias[bn0 + wn * 64 + ct * 16 + llo];
#pragma unroll
  for (int rt = 0; rt < 4; rt++) {
#pragma unroll
    for (int ct = 0; ct < 4; ct++) {
#pragma unroll
      for (int r = 0; r < 4; r++) {
        float v = acc[rt][ct][r] + bv4[ct];
        v = 0.5f * v * (1.0f + erff(v * 0.70710678118654752f));
        slab[(rt * 16 + lhi * 4 + r) * 76 + ct * 16 + llo] = f2bs(v);
      }
    }
  }
  const int rl0 = lane >> 3, cb8 = (lane & 7) << 3;
  const short* srd = slab + rl0 * 76 + cb8;
  short* Cw = C + (long)(bm0 + wm * 64 + rl0) * ldc + bn0 + wn * 64 + cb8;
#pragma unroll
  for (int j = 0; j < 8; j++) {
    short8 v = *(const short8*)(srd + j * 8 * 76);
    *(short8*)(Cw + (long)(j * 8) * ldc) = v;
  }
#undef STG
#undef BODY
}

// ---------- launch ----------
extern "C" void kernel_launch(void* const* d_in, const int* in_sizes, int n_in,
                              void* d_out, int out_size, void* d_ws, size_t ws_size,
                              hipStream_t stream) {
  const float* x   = (const float*)d_in[0];
  // d_in[1] = mask (int32) — unused in infer path
  const float* g1  = (const float*)d_in[2];
  const float* b1  = (const float*)d_in[3];
  const float* Wq  = (const float*)d_in[4];
  const float* bq  = (const float*)d_in[5];
  const float* Wk  = (const float*)d_in[6];
  const float* bk  = (const float*)d_in[7];
  const float* Wv  = (const float*)d_in[8];
  const float* bv  = (const float*)d_in[9];
  const float* g2  = (const float*)d_in[10];
  const float* b2  = (const float*)d_in[11];
  const float* W1  = (const float*)d_in[12];
  const float* bw1 = (const float*)d_in[13];
  const float* W2  = (const float*)d_in[14];
  const float* bw2 = (const float*)d_in[15];

  char* ws = (char*)d_ws;
  const long MB = 1024 * 1024;
  // layout (peak 137MB; ws >= 189MB proven in round 5):
  float* bQKV  = (float*)(ws);            // [3][1024] f32: bq | bk | bv8
  float* x1    = (float*)(ws + 1 * MB);   // [4096,1024] f32  [1,17)
  short* wqT   = (short*)(ws + 17 * MB);  // [17,19)
  short* wkT   = (short*)(ws + 19 * MB);  // [19,21)  contiguous with wqT
  short* wv8T  = (short*)(ws + 21 * MB);  // [21,23)  contiguous (z*2MB)
  short* xn    = (short*)(ws + 23 * MB);  // [23,31)
  short* Q     = (short*)(ws + 31 * MB);  // [31,39)
  short* Kb    = (short*)(ws + 39 * MB);  // [39,47)  contiguous with Q
  short* V8T   = (short*)(ws + 47 * MB);  // [32][128][1024] bf16 [47,55)
  // FFN overlay (attention scratch dead by then):
  short* xn2  = (short*)(ws + 17 * MB);  // [17,25)
  short* Hb   = (short*)(ws + 25 * MB);  // [25,57)
  short* w1T  = (short*)(ws + 57 * MB);  // [57,65)
  short* w2T  = (short*)(ws + 65 * MB);  // [65,73)
  float* part = (float*)(ws + 73 * MB);  // [4][4096,1024] f32 [73,137)

  // fused prep: pair-pipelined transposes + wv8 + biases + LN1
  prep_k<<<5638, 256, 0, stream>>>(x, g1, b1, xn,
                                   Wq, wqT, Wk, wkT, Wv, wv8T,
                                   W1, w1T, W2, w2T,
                                   bq, bk, bv, bQKV);

  // QKV: z=0 -> Q (pre-scaled), z=1 -> Kb, z=2 -> V8T (transposed). K=1024.
  gemm256<E_QKV><<<dim3(4, 16, 3), 512, 0, stream>>>(
      xn, 1024, 0, wqT, 1024, 1048576, bQKV, 1024,
      Q, 4194304, 1024, V8T, 1024);

  // fused attention: scores+softmax+PV8+head-sum+residual -> x1
  flash_k<<<dim3(16, 32), 256, 0, stream>>>(Q, Kb, V8T, x, x1);

  // ---- FFN phase ----
  ln_k<<<4096, 256, 0, stream>>>(x1, g2, b2, xn2);

  // FFN1 + exact GELU -> Hb (bf16): 128x256 tiles, 2 blocks/CU. K=1024.
  gemm128n_gelu<<<dim3(16, 32), 512, 0, stream>>>(
      xn2, 1024, w1T, 1024, bw1, Hb, 4096, 1024);

  // FFN2 split-K=4: f32 partials (balanced; residual+bias in reduce4).
  gemm256<E_PART><<<dim3(4, 16, 4), 512, 0, stream>>>(
      Hb, 4096, 1024, w2T, 4096, 1024, nullptr, 0,
      part, 4194304, 1024, nullptr, 1024);

  reduce4_k<<<4096, 256, 0, stream>>>(part, x1, bw2, (float*)d_out);
}

// Round 13
// 333.724 us; speedup vs baseline: 1.1169x; 1.0031x over previous
//
#include <hip/hip_runtime.h>
#include <hip/hip_bf16.h>
#include <math.h>

// ---------- types ----------
typedef __attribute__((ext_vector_type(8))) short   short8;
typedef __attribute__((ext_vector_type(4))) short   short4v;
typedef __attribute__((ext_vector_type(8))) __bf16  bf16x8;
typedef __attribute__((ext_vector_type(4))) float   f32x4;

typedef const __attribute__((address_space(1))) void cgv_t;
typedef __attribute__((address_space(3))) void lv_t;

__device__ __forceinline__ float bs2f(short s) {
  unsigned int u = ((unsigned int)(unsigned short)s) << 16;
  return __builtin_bit_cast(float, u);
}
__device__ __forceinline__ short f2bs(float f) {
  __hip_bfloat16 h = __float2bfloat16(f);  // RNE
  return __builtin_bit_cast(short, h);
}
// async global->LDS, 16B per lane; lds base must be wave-uniform
__device__ __forceinline__ void glds16(const short* g, short* l) {
  __builtin_amdgcn_global_load_lds((cgv_t*)g, (lv_t*)l, 16, 0, 0);
}

// B=4, S=1024, D=1024, H=8, FF=4096, DK=128. I/O f32; internals bf16.
// Head-sum trick: attn[s,g] = sum_k P[s,k] * V8[k,g], V8 = xn @ Wv8,
// Wv8[:,r] = sum_{e<8} Wv[:,8r+e]. Attention fused flash-style.
// Q is pre-scaled by (1/sqrt(128))*log2(e) at the QKV epilogue, so the
// flash softmax runs entirely in the exp2 domain (raw v_exp_f32).
// Reference's raw reshape: (b,h,s,gg) attn value lands at x1 flat index
// ((b*8+h)*1024+s)*128+gg (verified round 6/8).

// ---------- prep device bodies ----------
// transpose unit descriptor: out[C][R] = bf16(in[R][C]), 64x64 tile (bx,by)
struct TrU { const float* in; short* out; int R, C, bx, by; };

__device__ __forceinline__ TrU tr_decode(
    int u,
    const float* Wq, short* wqT, const float* Wk, short* wkT,
    const float* W1, short* w1T, const float* W2, short* w2T) {
  TrU s;
  if (u < 1024)      { s.in = W1; s.out = w1T; s.R = 1024; s.C = 4096; s.bx = u & 63; s.by = u >> 6; }
  else if (u < 2048) { int v = u - 1024; s.in = W2; s.out = w2T; s.R = 4096; s.C = 1024; s.bx = v & 15; s.by = v >> 4; }
  else if (u < 2304) { int v = u - 2048; s.in = Wq; s.out = wqT; s.R = 1024; s.C = 1024; s.bx = v & 15; s.by = v >> 4; }
  else               { int v = u - 2304; s.in = Wk; s.out = wkT; s.R = 1024; s.C = 1024; s.bx = v & 15; s.by = v >> 4; }
  return s;
}

// pair-pipelined double transpose: all 8 global loads issued up-front,
// both LDS writes, ONE sync, both read+store phases.
__device__ __forceinline__ void tr2_body(const TrU& A, const TrU& B,
                                         short* T0, short* T1) {
  const int t = threadIdx.x;
  const int rr = t >> 4, cc = (t & 15) << 2;
  f32x4 va[4], vb[4];
#pragma unroll
  for (int h = 0; h < 4; h++)
    va[h] = *(const f32x4*)(A.in + (long)(A.by * 64 + rr + h * 16) * A.C + A.bx * 64 + cc);
#pragma unroll
  for (int h = 0; h < 4; h++)
    vb[h] = *(const f32x4*)(B.in + (long)(B.by * 64 + rr + h * 16) * B.C + B.bx * 64 + cc);
#pragma unroll
  for (int h = 0; h < 4; h++)
#pragma unroll
    for (int e = 0; e < 4; e++) {
      T0[(rr + h * 16) * 72 + cc + e] = f2bs(va[h][e]);
      T1[(rr + h * 16) * 72 + cc + e] = f2bs(vb[h][e]);
    }
  __syncthreads();
  const int cr = t >> 3, rs = (t & 7) << 3;
#pragma unroll
  for (int hf = 0; hf < 2; hf++) {
    const int c = cr + hf * 32;
    short8 v0, v1;
#pragma unroll
    for (int e = 0; e < 8; e++) { v0[e] = T0[(rs + e) * 72 + c]; v1[e] = T1[(rs + e) * 72 + c]; }
    *(short8*)(A.out + (long)(A.bx * 64 + c) * A.R + A.by * 64 + rs) = v0;
    *(short8*)(B.out + (long)(B.bx * 64 + c) * B.R + B.by * 64 + rs) = v1;
  }
}

// wv8T[r][k] = bf16( sum_{e<8} Wv[k][8r+e] ); 64x64 tile
__device__ __forceinline__ void wv8_body(const float* __restrict__ Wv,
                                         short* __restrict__ out,
                                         int bx, int by, short* T) {
  const int r0 = bx * 64, k0 = by * 64;
  const int t = threadIdx.x;
  const int wave = t >> 6, lane = t & 63;
  const int r = r0 + lane;
#pragma unroll 4
  for (int i = 0; i < 16; i++) {
    const int k = k0 + wave * 16 + i;
    const float* src = Wv + (long)k * 8192 + 8 * r;
    f32x4 a = *(const f32x4*)src;
    f32x4 b = *(const f32x4*)(src + 4);
    float s = (a[0] + a[1] + a[2] + a[3]) + (b[0] + b[1] + b[2] + b[3]);
    T[lane * 72 + wave * 16 + i] = f2bs(s);
  }
  __syncthreads();
  const int rr = t >> 3, kc = (t & 7) << 3;
#pragma unroll
  for (int half = 0; half < 2; half++) {
    const int rl = rr + half * 32;
    *(short8*)(out + (long)(r0 + rl) * 1024 + k0 + kc) = *(const short8*)&T[rl * 72 + kc];
  }
}

// layernorm row of 1024; f32 in/params; bf16 out
__device__ __forceinline__ void ln_body(const float* __restrict__ in,
                                        const float* __restrict__ g,
                                        const float* __restrict__ b,
                                        short* __restrict__ out, int row,
                                        float* rs, float* rq) {
  const int t = threadIdx.x;
  const long base = (long)row * 1024 + t * 4;
  f32x4 f = *(const f32x4*)(in + base);
  float v[4] = {f[0], f[1], f[2], f[3]};
  float s1 = v[0] + v[1] + v[2] + v[3];
  float s2 = v[0]*v[0] + v[1]*v[1] + v[2]*v[2] + v[3]*v[3];
#pragma unroll
  for (int off = 32; off; off >>= 1) {
    s1 += __shfl_xor(s1, off);
    s2 += __shfl_xor(s2, off);
  }
  if ((t & 63) == 0) { rs[t >> 6] = s1; rq[t >> 6] = s2; }
  __syncthreads();
  s1 = rs[0] + rs[1] + rs[2] + rs[3];
  s2 = rq[0] + rq[1] + rq[2] + rq[3];
  const float mean = s1 * (1.0f / 1024.0f);
  const float var  = s2 * (1.0f / 1024.0f) - mean * mean;
  const float rstd = rsqrtf(var + 1e-5f);
  f32x4 gv = *(const f32x4*)(g + t * 4);
  f32x4 bv = *(const f32x4*)(b + t * 4);
  short4v o;
#pragma unroll
  for (int i = 0; i < 4; i++)
    o[i] = f2bs((v[i] - mean) * rstd * gv[i] + bv[i]);
  *(short4v*)(out + base) = o;
}

// ---------- fused prep ----------
// [0,1280): tr pairs (units 2b, 2b+1 of 2560: W1|W2|Wq|Wk)
// [1280,1536): wv8 tiles | [1536,1540): bv8 | 1540,1541: bq/bk copy
// [1542, 5638): LN1 rows. Total 5638 blocks.
__global__ __launch_bounds__(256) void prep_k(
    const float* __restrict__ x, const float* __restrict__ g1,
    const float* __restrict__ b1, short* __restrict__ xn,
    const float* __restrict__ Wq, short* __restrict__ wqT,
    const float* __restrict__ Wk, short* __restrict__ wkT,
    const float* __restrict__ Wv, short* __restrict__ wv8T,
    const float* __restrict__ W1, short* __restrict__ w1T,
    const float* __restrict__ W2, short* __restrict__ w2T,
    const float* __restrict__ bq, const float* __restrict__ bk,
    const float* __restrict__ bv, float* __restrict__ bQKV) {
  __shared__ __align__(16) short T[2][64 * 72];
  __shared__ float rs[4], rq[4];
  const int t = threadIdx.x;
  int bid = blockIdx.x;
  if (bid < 1280) {
    TrU A = tr_decode(bid * 2,     Wq, wqT, Wk, wkT, W1, w1T, W2, w2T);
    TrU B = tr_decode(bid * 2 + 1, Wq, wqT, Wk, wkT, W1, w1T, W2, w2T);
    tr2_body(A, B, T[0], T[1]);
    return;
  }
  bid -= 1280;
  if (bid < 256) { wv8_body(Wv, wv8T, bid & 15, bid >> 4, T[0]); return; }
  bid -= 256;
  if (bid < 4) {
    const int r = bid * 256 + t;
    f32x4 a = *(const f32x4*)(bv + 8 * r);
    f32x4 b = *(const f32x4*)(bv + 8 * r + 4);
    bQKV[2048 + r] = (a[0] + a[1] + a[2] + a[3]) + (b[0] + b[1] + b[2] + b[3]);
    return;
  }
  bid -= 4;
  if (bid == 0) { *(f32x4*)(bQKV + t * 4) = *(const f32x4*)(bq + t * 4); return; }
  if (bid == 1) { *(f32x4*)(bQKV + 1024 + t * 4) = *(const f32x4*)(bk + t * 4); return; }
  ln_body(x, g1, b1, xn, bid - 2, rs, rq);
}

// ---------- layernorm kernel (2nd LN: x1 -> xn2) ----------
__global__ __launch_bounds__(256) void ln_k(const float* __restrict__ in,
                                            const float* __restrict__ g,
                                            const float* __restrict__ b,
                                            short* __restrict__ out) {
  __shared__ float rs[4], rq[4];
  ln_body(in, g, b, out, blockIdx.x, rs, rq);
}

// ---------- split-K=4 reduce: d_out = p0..p3 + x1 + bias ----------
__global__ __launch_bounds__(256) void reduce4_k(const float* __restrict__ p,
                                                 const float* __restrict__ x1,
                                                 const float* __restrict__ bias,
                                                 float* __restrict__ out) {
  const int t = threadIdx.x;
  const long base = (long)blockIdx.x * 1024 + t * 4;
  f32x4 a = *(const f32x4*)(p + base);
  f32x4 b = *(const f32x4*)(p + 4194304 + base);
  f32x4 c = *(const f32x4*)(p + 8388608 + base);
  f32x4 d = *(const f32x4*)(p + 12582912 + base);
  f32x4 e = *(const f32x4*)(x1 + base);
  f32x4 g = *(const f32x4*)(bias + t * 4);
  *(f32x4*)(out + base) = a + b + c + d + e + g;
}

// ---------- fused flash attention (+head-sum + residual) ----------
// Q pre-scaled by SC*log2e; softmax in exp2 domain; defer-max (THR=8,
// exact: m cancels in o/l). XCD swizzle: XCD r owns bh in [4r,4r+4) so
// its K/V working set (2MB) is L2-resident. T2 XOR swizzle on LDS slabs.
__global__ __launch_bounds__(256, 2) void flash_k(
    const short* __restrict__ Qg_, const short* __restrict__ Kg_,
    const short* __restrict__ V8T, const float* __restrict__ xg,
    float* __restrict__ x1) {
  __shared__ __align__(16) short smem[40960];  // 80 KB exactly
  short* Qs = smem;            // 4 * [64][32]  (slab 2048 shorts)
  short* Ks = smem + 8192;     // 4 * [128][32] (slab 4096); P reuses rows 0..63
  short* Vs = smem + 24576;    // 4 * [128][32]

  const int t = threadIdx.x;
  const int wave = t >> 6, lane = t & 63;
  const int llo = lane & 15, lhi = lane >> 4;

  // XCD-grouped remap: 512 blocks, XCD r <- bh in [4r, 4r+4), all 16 q-tiles
  int lin = blockIdx.x + (blockIdx.y << 4);
  lin = (lin & 7) * 64 + (lin >> 3);
  const int q0 = (lin & 15) * 64;
  const int bh = lin >> 4, b = bh >> 3, h = bh & 7;

  const short* Qg = Qg_ + ((long)(b * 1024 + q0)) * 1024 + h * 128;
  const short* Kg = Kg_ + ((long)b * 1024) * 1024 + h * 128;
  const short* Vg = V8T + (long)bh * 131072;   // [128 g][1024 s]

  const int srow = t >> 2;
  const int sgc = (((t & 3) ^ ((t >> 3) & 3)) << 3);  // pre-swizzled src chunk
  const int wbase = wave * 512;          // wave-uniform stage base (shorts)
  const int swzo = ((lhi ^ ((llo >> 1) & 3)) << 3);   // swizzled frag chunk
  const int arow = (wave * 16 + llo) * 32 + swzo;     // Q / P frag read

#pragma unroll
  for (int kk = 0; kk < 4; kk++)
    glds16(Qg + (long)srow * 1024 + kk * 32 + sgc, Qs + kk * 2048 + wbase);

  f32x4 o[8];
  float mR[4], lR[4];
#pragma unroll
  for (int i = 0; i < 8; i++) o[i] = f32x4{0.f, 0.f, 0.f, 0.f};
#pragma unroll
  for (int r = 0; r < 4; r++) { mR[r] = -1e30f; lR[r] = 0.f; }

  for (int it = 0; it < 8; it++) {
    const int kt0 = it * 128;
#pragma unroll
    for (int kk = 0; kk < 4; kk++) {
      glds16(Kg + (long)(kt0 + srow) * 1024 + kk * 32 + sgc,
             Ks + kk * 4096 + wbase);
      glds16(Kg + (long)(kt0 + 64 + srow) * 1024 + kk * 32 + sgc,
             Ks + kk * 4096 + 2048 + wbase);
      glds16(Vg + (long)srow * 1024 + kt0 + kk * 32 + sgc,
             Vs + kk * 4096 + wbase);
      glds16(Vg + (long)(64 + srow) * 1024 + kt0 + kk * 32 + sgc,
             Vs + kk * 4096 + 2048 + wbase);
    }
    __syncthreads();

    f32x4 s[8];
#pragma unroll
    for (int i = 0; i < 8; i++) s[i] = f32x4{0.f, 0.f, 0.f, 0.f};
#pragma unroll
    for (int kk = 0; kk < 4; kk++) {
      bf16x8 aq = *(const bf16x8*)(Qs + kk * 2048 + arow);
#pragma unroll
      for (int ct = 0; ct < 8; ct++) {
        bf16x8 bk = *(const bf16x8*)(Ks + kk * 4096 + (ct * 16 + llo) * 32 + swzo);
        s[ct] = __builtin_amdgcn_mfma_f32_16x16x32_bf16(aq, bk, s[ct], 0, 0, 0);
      }
    }
    // scores already scaled by SC*log2e (folded into Q); exp2 domain
    float mt[4];
#pragma unroll
    for (int r = 0; r < 4; r++) {
      float m = s[0][r];
#pragma unroll
      for (int ct = 1; ct < 8; ct++) m = fmaxf(m, s[ct][r]);
      m = fmaxf(m, __shfl_xor(m, 1));
      m = fmaxf(m, __shfl_xor(m, 2));
      m = fmaxf(m, __shfl_xor(m, 4));
      m = fmaxf(m, __shfl_xor(m, 8));
      mt[r] = m;
    }
    // defer-max: only rescale when max grew by > 8 (P bounded by 2^8)
    bool need = (mt[0] > mR[0] + 8.f) | (mt[1] > mR[1] + 8.f) |
                (mt[2] > mR[2] + 8.f) | (mt[3] > mR[3] + 8.f);
    if (__any(need)) {
      float alpha[4];
#pragma unroll
      for (int r = 0; r < 4; r++) {
        const float mn = fmaxf(mR[r], mt[r]);
        alpha[r] = __builtin_amdgcn_exp2f(mR[r] - mn);
        mR[r] = mn;
        lR[r] *= alpha[r];
      }
#pragma unroll
      for (int ct = 0; ct < 8; ct++)
#pragma unroll
        for (int r = 0; r < 4; r++) o[ct][r] *= alpha[r];
    }
#pragma unroll
    for (int ct = 0; ct < 8; ct++)
#pragma unroll
      for (int r = 0; r < 4; r++)
        s[ct][r] = __builtin_amdgcn_exp2f(s[ct][r] - mR[r]);
#pragma unroll
    for (int r = 0; r < 4; r++) {
      float ls = s[0][r];
#pragma unroll
      for (int ct = 1; ct < 8; ct++) ls += s[ct][r];
      ls += __shfl_xor(ls, 1);
      ls += __shfl_xor(ls, 2);
      ls += __shfl_xor(ls, 4);
      ls += __shfl_xor(ls, 8);
      lR[r] += ls;
    }
    __syncthreads();

    // P -> Ks rows 0..63, swizzled slots (col' matches swizzled P-read)
#pragma unroll
    for (int ct = 0; ct < 8; ct++) {
      const int chunk = ((ct & 1) << 1) | (llo >> 3);
      const int cl = llo & 7;
#pragma unroll
      for (int r = 0; r < 4; r++) {
        const int row = wave * 16 + lhi * 4 + r;
        const int xr = ((lhi << 1) | (r >> 1)) & 3;
        Ks[(ct >> 1) * 4096 + row * 32 + (((chunk ^ xr) << 3) | cl)] = f2bs(s[ct][r]);
      }
    }
    __syncthreads();

#pragma unroll
    for (int kk = 0; kk < 4; kk++) {
      bf16x8 ap = *(const bf16x8*)(Ks + kk * 4096 + arow);
#pragma unroll
      for (int ct = 0; ct < 8; ct++) {
        bf16x8 bv = *(const bf16x8*)(Vs + kk * 4096 + (ct * 16 + llo) * 32 + swzo);
        o[ct] = __builtin_amdgcn_mfma_f32_16x16x32_bf16(ap, bv, o[ct], 0, 0, 0);
      }
    }
    __syncthreads();
  }

  float inv[4];
#pragma unroll
  for (int r = 0; r < 4; r++) inv[r] = 1.0f / lR[r];
#pragma unroll
  for (int ct = 0; ct < 8; ct++) {
#pragma unroll
    for (int r = 0; r < 4; r++) {
      const int row = q0 + wave * 16 + lhi * 4 + r;
      const long idx = ((long)(b * 8 + h) * 1024 + row) * 128 + ct * 16 + llo;
      x1[idx] = xg[idx] + o[ct][r] * inv[r];
    }
  }
}

// ======================================================================
// 256x256 8-phase bf16 GEMM (T1 XCD swizzle + T2 swizzle + T3/T4 counted
// vmcnt + T5 setprio). 512 thr = 8 waves (2M x 4N), per-wave out 128x64,
// BK=64 (2 K-halves). LDS 128 KiB STATIC. One trailing barrier per phase.
// Used for QKV only (192 blocks at 1/CU; 128-tile split is a wash there).
// Epilogues: E_QKV (bias->bf16; z==0 scaled by SC*log2e; z==2 ->
// transposed write into V8T head layout via aux).
// Per-z offsets: A += z*azk, Bt += z*bzk (shorts), bias += z*biasl.
// Requires NT=K/64 even, >=4; grid blocks %8 == 0.
// ======================================================================
enum { E_GELU = 0, E_QKV = 1, E_PART = 2 };

#define MF16(va, vb, vc) __builtin_amdgcn_mfma_f32_16x16x32_bf16(va, vb, vc, 0, 0, 0)
#define VMW(n) asm volatile("s_waitcnt vmcnt(" #n ")" ::: "memory")
#define NOPS ((void)0)

#define STAGE_A(BUF, KH, KB) do {                                          \
    glds16(Ag + (KB), smem + ((BUF) * 2 + (KH)) * 8192 + wofs);            \
    glds16(Ag2 + (KB), smem + ((BUF) * 2 + (KH)) * 8192 + 4096 + wofs);    \
  } while (0)
#define STAGE_B(BUF, KH, KB) do {                                          \
    glds16(Bg + (KB), smem + 32768 + ((BUF) * 2 + (KH)) * 8192 + wofs);    \
    glds16(Bg2 + (KB), smem + 32768 + ((BUF) * 2 + (KH)) * 8192 + 4096 + wofs); \
  } while (0)

// LOADB=1 -> load vb0..vb3 (B frags) this phase; LOADB=0 -> reuse.
#define PHASE(RH, KH, BUF, LOADB, STAGE_STMT, WAIT_STMT)                   \
  {                                                                        \
    const short* Ar_ = smem + ((BUF) * 2 + (KH)) * 8192 + aoff + (RH) * 2048; \
    bf16x8 a0 = *(const bf16x8*)(Ar_);                                     \
    bf16x8 a1 = *(const bf16x8*)(Ar_ + 512);                               \
    bf16x8 a2 = *(const bf16x8*)(Ar_ + 1024);                              \
    bf16x8 a3 = *(const bf16x8*)(Ar_ + 1536);                              \
    if (LOADB) {                                                           \
      const short* Br_ = smem + 32768 + ((BUF) * 2 + (KH)) * 8192 + boff;  \
      vb0 = *(const bf16x8*)(Br_);                                         \
      vb1 = *(const bf16x8*)(Br_ + 512);                                   \
      vb2 = *(const bf16x8*)(Br_ + 1024);                                  \
      vb3 = *(const bf16x8*)(Br_ + 1536);                                  \
    }                                                                      \
    STAGE_STMT;                                                            \
    __builtin_amdgcn_s_setprio(1);                                         \
    acc[(RH) * 4 + 0][0] = MF16(a0, vb0, acc[(RH) * 4 + 0][0]);            \
    acc[(RH) * 4 + 0][1] = MF16(a0, vb1, acc[(RH) * 4 + 0][1]);            \
    acc[(RH) * 4 + 0][2] = MF16(a0, vb2, acc[(RH) * 4 + 0][2]);            \
    acc[(RH) * 4 + 0][3] = MF16(a0, vb3, acc[(RH) * 4 + 0][3]);            \
    acc[(RH) * 4 + 1][0] = MF16(a1, vb0, acc[(RH) * 4 + 1][0]);            \
    acc[(RH) * 4 + 1][1] = MF16(a1, vb1, acc[(RH) * 4 + 1][1]);            \
    acc[(RH) * 4 + 1][2] = MF16(a1, vb2, acc[(RH) * 4 + 1][2]);            \
    acc[(RH) * 4 + 1][3] = MF16(a1, vb3, acc[(RH) * 4 + 1][3]);            \
    acc[(RH) * 4 + 2][0] = MF16(a2, vb0, acc[(RH) * 4 + 2][0]);            \
    acc[(RH) * 4 + 2][1] = MF16(a2, vb1, acc[(RH) * 4 + 2][1]);            \
    acc[(RH) * 4 + 2][2] = MF16(a2, vb2, acc[(RH) * 4 + 2][2]);            \
    acc[(RH) * 4 + 2][3] = MF16(a2, vb3, acc[(RH) * 4 + 2][3]);            \
    acc[(RH) * 4 + 3][0] = MF16(a3, vb0, acc[(RH) * 4 + 3][0]);            \
    acc[(RH) * 4 + 3][1] = MF16(a3, vb1, acc[(RH) * 4 + 3][1]);            \
    acc[(RH) * 4 + 3][2] = MF16(a3, vb2, acc[(RH) * 4 + 3][2]);            \
    acc[(RH) * 4 + 3][3] = MF16(a3, vb3, acc[(RH) * 4 + 3][3]);            \
    __builtin_amdgcn_s_setprio(0);                                         \
    WAIT_STMT;                                                             \
    __builtin_amdgcn_sched_barrier(0);                                     \
    __builtin_amdgcn_s_barrier();                                          \
    __builtin_amdgcn_sched_barrier(0);                                     \
  }

#define TILE8(T, BUF)                                                        \
  PHASE(0, 0, BUF, 1, STAGE_A(1 - (BUF), 1, ((T) + 1) * 64 + 32), NOPS);     \
  PHASE(1, 0, BUF, 0, STAGE_B(1 - (BUF), 1, ((T) + 1) * 64 + 32), VMW(8));   \
  PHASE(0, 1, BUF, 1, STAGE_A(BUF, 0, ((T) + 2) * 64), NOPS);                \
  PHASE(1, 1, BUF, 0, STAGE_B(BUF, 0, ((T) + 2) * 64), VMW(8))

template <int EPI>
__global__ __launch_bounds__(512, 2) void gemm256(
    const short* __restrict__ A, int lda, long azk,
    const short* __restrict__ Bt, int ldb, long bzk,
    const float* __restrict__ bias, long biasl,
    void* __restrict__ outp, long czl, int ldc,
    void* __restrict__ aux, int K) {
  __shared__ __align__(16) short smem[65536];  // 128 KiB static

  const int t = threadIdx.x;
  const int wave = t >> 6, lane = t & 63;
  const int llo = lane & 15, lhi = lane >> 4;
  const int wm = wave >> 2, wn = wave & 3;

  // XCD-chunked bijective remap: keep x-partners (shared A panel) on one XCD
  int lin = blockIdx.x + gridDim.x * (blockIdx.y + gridDim.y * blockIdx.z);
  const int nwg = gridDim.x * gridDim.y * gridDim.z;  // % 8 == 0
  lin = (lin & 7) * (nwg >> 3) + (lin >> 3);
  const int bx = lin % gridDim.x;
  const int rem = lin / gridDim.x;
  const int by = rem % gridDim.y;
  const int z = rem / gridDim.y;

  const int bm0 = by * 256, bn0 = bx * 256;
  A += (long)z * azk;
  Bt += (long)z * bzk;

  // staging constants: thread loads rows (srow, srow+128), chunk pre-swizzled
  const int srow = t >> 2;                                 // 0..127
  const int sgc = (((t & 3) ^ ((t >> 3) & 3)) << 3);       // source chunk (shorts)
  const short* Ag  = A  + (long)(bm0 + srow) * lda + sgc;
  const short* Ag2 = A  + (long)(bm0 + 128 + srow) * lda + sgc;
  const short* Bg  = Bt + (long)(bn0 + srow) * ldb + sgc;
  const short* Bg2 = Bt + (long)(bn0 + 128 + srow) * ldb + sgc;
  const int wofs = wave * 512;                             // wave-uniform LDS base

  // fragment read constants (rows within region are multiples of 16 + llo)
  const int swz = ((lhi ^ ((llo >> 1) & 3)) << 3);
  const int aoff = (wm * 128 + llo) * 32 + swz;            // + RH*2048 + rt*512
  const int boff = (wn * 64 + llo) * 32 + swz;             // + ct*512

  f32x4 acc[8][4];
#pragma unroll
  for (int i = 0; i < 8; i++)
#pragma unroll
    for (int j = 0; j < 4; j++) acc[i][j] = f32x4{0.f, 0.f, 0.f, 0.f};
  bf16x8 vb0, vb1, vb2, vb3;  // B frags, loaded at RH=0, reused at RH=1

  const int NT = K >> 6;  // even, >= 4

  // prologue: tile0 (both K-halves) + tile1 K-half0; keep newest 8 in flight
  STAGE_A(0, 0, 0);  STAGE_B(0, 0, 0);
  STAGE_A(0, 1, 32); STAGE_B(0, 1, 32);
  STAGE_A(1, 0, 64); STAGE_B(1, 0, 64);
  VMW(8);
  __builtin_amdgcn_sched_barrier(0);
  __builtin_amdgcn_s_barrier();
  __builtin_amdgcn_sched_barrier(0);

  for (int tt = 0; tt < NT - 2; tt += 2) {
    TILE8(tt, 0);
    TILE8(tt + 1, 1);
  }
  // tail tile NT-2 (buf 0): stage only tile NT-1's K-half1
  PHASE(0, 0, 0, 1, STAGE_A(1, 1, (NT - 1) * 64 + 32), NOPS);
  PHASE(1, 0, 0, 0, STAGE_B(1, 1, (NT - 1) * 64 + 32), VMW(8));
  PHASE(0, 1, 0, 1, NOPS, NOPS);
  PHASE(1, 1, 0, 0, NOPS, VMW(4));
  // tail tile NT-1 (buf 1): no staging
  PHASE(0, 0, 1, 1, NOPS, NOPS);
  PHASE(1, 0, 1, 0, NOPS, VMW(0));
  PHASE(0, 1, 1, 1, NOPS, NOPS);
  PHASE(1, 1, 1, 0, NOPS, NOPS);

  if (EPI == E_QKV && z == 2) {
    // V8 projection: transposed write into V8T[bh][g][s] via per-wave slab
    short* slab = smem + wave * 4352;   // [64 cols][68] shorts
    const int bb = bm0 >> 10, sbase = (bm0 & 1023) + wm * 128;
    float bv4[4];
#pragma unroll
    for (int ct = 0; ct < 4; ct++)
      bv4[ct] = bias[z * biasl + bn0 + wn * 64 + ct * 16 + llo];
    const int gcol = bn0 + wn * 64 + lane;
    short* dst0 = (short*)aux + ((long)(bb * 8 + (gcol >> 7))) * 131072 +
                  (long)(gcol & 127) * 1024 + sbase;
#pragma unroll
    for (int p = 0; p < 2; p++) {
#pragma unroll
      for (int rt4 = 0; rt4 < 4; rt4++) {
#pragma unroll
        for (int ct = 0; ct < 4; ct++) {
#pragma unroll
          for (int r = 0; r < 4; r++) {
            float v = acc[p * 4 + rt4][ct][r] + bv4[ct];
            slab[(ct * 16 + llo) * 68 + rt4 * 16 + lhi * 4 + r] = f2bs(v);
          }
        }
      }
#pragma unroll
      for (int j = 0; j < 8; j++)
        *(short8*)(dst0 + p * 64 + j * 8) = *(const short8*)&slab[lane * 68 + j * 8];
    }
  } else {
    // bias (+Qscale) -> bf16 via per-wave LDS slab -> short8 stores
    short* C = (short*)outp + (long)z * czl;
    short* slab = smem + wave * 4864;   // [64 rows][76 cols] shorts
    float bv4[4];
#pragma unroll
    for (int ct = 0; ct < 4; ct++)
      bv4[ct] = bias[z * biasl + bn0 + wn * 64 + ct * 16 + llo];
    const int rl0 = lane >> 3, cb8 = (lane & 7) << 3;
    const short* srd = slab + rl0 * 76 + cb8;
    short* Cw = C + (long)(bm0 + wm * 128 + rl0) * ldc + bn0 + wn * 64 + cb8;
#pragma unroll
    for (int p = 0; p < 2; p++) {
#pragma unroll
      for (int rt4 = 0; rt4 < 4; rt4++) {
#pragma unroll
        for (int ct = 0; ct < 4; ct++) {
#pragma unroll
          for (int r = 0; r < 4; r++) {
            float v = acc[p * 4 + rt4][ct][r] + bv4[ct];
            if (EPI == E_QKV && z == 0)
              v *= 0.12751744476582f;  // (1/sqrt(128)) * log2(e)
            slab[(rt4 * 16 + lhi * 4 + r) * 76 + ct * 16 + llo] = f2bs(v);
          }
        }
      }
#pragma unroll
      for (int j = 0; j < 8; j++) {
        short8 v = *(const short8*)(srd + j * 8 * 76);
        *(short8*)(Cw + ((long)p * 64 + j * 8) * ldc) = v;
      }
    }
  }
}

// ======================================================================
// FFN1: 128x256 bf16 GEMM + GELU, 2 blocks/CU (cross-block overlap).
// 512 thr = 8 waves (2M x 4N), per-wave out 64x64 (acc 4x4 f32x4 = 64 AGPR).
// BK=32 classic double-buffer, counted vmcnt(3) (never 0 in loop).
// LDS: staging 2 bufs x (A[128][32] + B[256][32]) = 24576 shorts;
// epilogue slabs 8 x [64][76] = 38912 shorts -> block LDS 77824 B -> 2/CU.
// T2 swizzle identical to gemm256 (pre-swizzled source + swizzled reads).
// Body: {ds_read frags; MFMA; barrier; stage i+2 into cur; VMW; barrier}.
// Grid (16,32) = 512 blocks = 2/CU; XCD-chunked remap.
// ======================================================================
__global__ __launch_bounds__(512, 4) void gemm128n_gelu(
    const short* __restrict__ A, int lda,
    const short* __restrict__ Bt, int ldb,
    const float* __restrict__ bias,
    short* __restrict__ C, int ldc, int K) {
  __shared__ __align__(16) short smem[38912];

  const int t = threadIdx.x;
  const int wave = t >> 6, lane = t & 63;
  const int llo = lane & 15, lhi = lane >> 4;
  const int wm = wave >> 2, wn = wave & 3;

  int lin = blockIdx.x + (blockIdx.y << 4);  // gridDim = (16,32)
  lin = (lin & 7) * 64 + (lin >> 3);
  const int bn0 = (lin & 15) * 256;
  const int bm0 = (lin >> 4) * 128;

  const int srow = t >> 2;
  const int sgc = (((t & 3) ^ ((t >> 3) & 3)) << 3);
  const short* Ag  = A  + (long)(bm0 + srow) * lda + sgc;
  const short* Bg  = Bt + (long)(bn0 + srow) * ldb + sgc;
  const short* Bg2 = Bt + (long)(bn0 + 128 + srow) * ldb + sgc;
  const int wofs = wave * 512;

  const int swz = ((lhi ^ ((llo >> 1) & 3)) << 3);
  const int aoff = (wm * 64 + llo) * 32 + swz;   // + rt*512 within A region
  const int boff = (wn * 64 + llo) * 32 + swz;   // + ct*512 within B region

  f32x4 acc[4][4];
#pragma unroll
  for (int i = 0; i < 4; i++)
#pragma unroll
    for (int j = 0; j < 4; j++) acc[i][j] = f32x4{0.f, 0.f, 0.f, 0.f};

#define STG(BUF, KB) do {                                                  \
    glds16(Ag + (KB), smem + (BUF) * 12288 + wofs);                        \
    glds16(Bg + (KB), smem + (BUF) * 12288 + 4096 + wofs);                 \
    glds16(Bg2 + (KB), smem + (BUF) * 12288 + 8192 + wofs);                \
  } while (0)

#define BODY(BUF, STAGE_STMT, WAIT_STMT)                                   \
  {                                                                        \
    const short* Ab_ = smem + (BUF) * 12288 + aoff;                        \
    const short* Bb_ = smem + (BUF) * 12288 + 4096 + boff;                 \
    bf16x8 a0 = *(const bf16x8*)(Ab_);                                     \
    bf16x8 a1 = *(const bf16x8*)(Ab_ + 512);                               \
    bf16x8 a2 = *(const bf16x8*)(Ab_ + 1024);                              \
    bf16x8 a3 = *(const bf16x8*)(Ab_ + 1536);                              \
    bf16x8 b0 = *(const bf16x8*)(Bb_);                                     \
    bf16x8 b1 = *(const bf16x8*)(Bb_ + 512);                               \
    bf16x8 b2 = *(const bf16x8*)(Bb_ + 1024);                              \
    bf16x8 b3 = *(const bf16x8*)(Bb_ + 1536);                              \
    __builtin_amdgcn_s_setprio(1);                                         \
    acc[0][0] = MF16(a0, b0, acc[0][0]); acc[0][1] = MF16(a0, b1, acc[0][1]); \
    acc[0][2] = MF16(a0, b2, acc[0][2]); acc[0][3] = MF16(a0, b3, acc[0][3]); \
    acc[1][0] = MF16(a1, b0, acc[1][0]); acc[1][1] = MF16(a1, b1, acc[1][1]); \
    acc[1][2] = MF16(a1, b2, acc[1][2]); acc[1][3] = MF16(a1, b3, acc[1][3]); \
    acc[2][0] = MF16(a2, b0, acc[2][0]); acc[2][1] = MF16(a2, b1, acc[2][1]); \
    acc[2][2] = MF16(a2, b2, acc[2][2]); acc[2][3] = MF16(a2, b3, acc[2][3]); \
    acc[3][0] = MF16(a3, b0, acc[3][0]); acc[3][1] = MF16(a3, b1, acc[3][1]); \
    acc[3][2] = MF16(a3, b2, acc[3][2]); acc[3][3] = MF16(a3, b3, acc[3][3]); \
    __builtin_amdgcn_s_setprio(0);                                         \
    __builtin_amdgcn_sched_barrier(0);                                     \
    __builtin_amdgcn_s_barrier();                                          \
    __builtin_amdgcn_sched_barrier(0);                                     \
    STAGE_STMT;                                                            \
    WAIT_STMT;                                                             \
    __builtin_amdgcn_sched_barrier(0);                                     \
    __builtin_amdgcn_s_barrier();                                          \
    __builtin_amdgcn_sched_barrier(0);                                     \
  }

  const int NT = K >> 5;  // 32 for K=1024; even, >= 4

  // prologue: stage first two K-steps; wait for step0 (3 newest in flight)
  STG(0, 0);
  STG(1, 32);
  VMW(3);
  __builtin_amdgcn_sched_barrier(0);
  __builtin_amdgcn_s_barrier();
  __builtin_amdgcn_sched_barrier(0);

  for (int i = 0; i < NT - 2; i += 2) {
    BODY(0, STG(0, (i + 2) * 32), VMW(3));
    BODY(1, STG(1, (i + 3) * 32), VMW(3));
  }
  BODY(0, NOPS, VMW(0));
  BODY(1, NOPS, NOPS);

  // epilogue: bias + exact GELU -> per-wave slab [64][76] -> short8 stores
  short* slab = smem + wave * 4864;
  float bv4[4];
#pragma unroll
  for (int ct = 0; ct < 4; ct++) bv4[ct] = bias[bn0 + wn * 64 + ct * 16 + llo];
#pragma unroll
  for (int rt = 0; rt < 4; rt++) {
#pragma unroll
    for (int ct = 0; ct < 4; ct++) {
#pragma unroll
      for (int r = 0; r < 4; r++) {
        float v = acc[rt][ct][r] + bv4[ct];
        v = 0.5f * v * (1.0f + erff(v * 0.70710678118654752f));
        slab[(rt * 16 + lhi * 4 + r) * 76 + ct * 16 + llo] = f2bs(v);
      }
    }
  }
  const int rl0 = lane >> 3, cb8 = (lane & 7) << 3;
  const short* srd = slab + rl0 * 76 + cb8;
  short* Cw = C + (long)(bm0 + wm * 64 + rl0) * ldc + bn0 + wn * 64 + cb8;
#pragma unroll
  for (int j = 0; j < 8; j++) {
    short8 v = *(const short8*)(srd + j * 8 * 76);
    *(short8*)(Cw + (long)(j * 8) * ldc) = v;
  }
#undef STG
#undef BODY
}

// ======================================================================
// FFN2: 128x256 bf16 GEMM, f32 split-K partials (E_PART). Same proven
// K-loop as gemm128n_gelu (duplicated, not templated, to avoid codegen
// perturbation of the proven kernel). No epilogue slab -> LDS 48 KiB ->
// 3 blocks/CU residency. Grid (4,32,4) = 512 blocks; XCD-chunked remap.
// Per z: A += z*azk, Bt += z*bzk (shorts), out P + z*czl (f32).
// ======================================================================
__global__ __launch_bounds__(512, 4) void gemm128n_part(
    const short* __restrict__ A, int lda, long azk,
    const short* __restrict__ Bt, int ldb, long bzk,
    float* __restrict__ P0, long czl, int ldc, int K) {
  __shared__ __align__(16) short smem[24576];

  const int t = threadIdx.x;
  const int wave = t >> 6, lane = t & 63;
  const int llo = lane & 15, lhi = lane >> 4;
  const int wm = wave >> 2, wn = wave & 3;

  int lin = blockIdx.x + gridDim.x * (blockIdx.y + gridDim.y * blockIdx.z);
  const int nwg = gridDim.x * gridDim.y * gridDim.z;  // % 8 == 0
  lin = (lin & 7) * (nwg >> 3) + (lin >> 3);
  const int bx = lin % gridDim.x;
  const int rem = lin / gridDim.x;
  const int by = rem % gridDim.y;
  const int z = rem / gridDim.y;

  const int bn0 = bx * 256, bm0 = by * 128;
  A += (long)z * azk;
  Bt += (long)z * bzk;

  const int srow = t >> 2;
  const int sgc = (((t & 3) ^ ((t >> 3) & 3)) << 3);
  const short* Ag  = A  + (long)(bm0 + srow) * lda + sgc;
  const short* Bg  = Bt + (long)(bn0 + srow) * ldb + sgc;
  const short* Bg2 = Bt + (long)(bn0 + 128 + srow) * ldb + sgc;
  const int wofs = wave * 512;

  const int swz = ((lhi ^ ((llo >> 1) & 3)) << 3);
  const int aoff = (wm * 64 + llo) * 32 + swz;
  const int boff = (wn * 64 + llo) * 32 + swz;

  f32x4 acc[4][4];
#pragma unroll
  for (int i = 0; i < 4; i++)
#pragma unroll
    for (int j = 0; j < 4; j++) acc[i][j] = f32x4{0.f, 0.f, 0.f, 0.f};

#define STGP(BUF, KB) do {                                                 \
    glds16(Ag + (KB), smem + (BUF) * 12288 + wofs);                        \
    glds16(Bg + (KB), smem + (BUF) * 12288 + 4096 + wofs);                 \
    glds16(Bg2 + (KB), smem + (BUF) * 12288 + 8192 + wofs);                \
  } while (0)

#define BODYP(BUF, STAGE_STMT, WAIT_STMT)                                  \
  {                                                                        \
    const short* Ab_ = smem + (BUF) * 12288 + aoff;                        \
    const short* Bb_ = smem + (BUF) * 12288 + 4096 + boff;                 \
    bf16x8 a0 = *(const bf16x8*)(Ab_);                                     \
    bf16x8 a1 = *(const bf16x8*)(Ab_ + 512);                               \
    bf16x8 a2 = *(const bf16x8*)(Ab_ + 1024);                              \
    bf16x8 a3 = *(const bf16x8*)(Ab_ + 1536);                              \
    bf16x8 b0 = *(const bf16x8*)(Bb_);                                     \
    bf16x8 b1 = *(const bf16x8*)(Bb_ + 512);                               \
    bf16x8 b2 = *(const bf16x8*)(Bb_ + 1024);                              \
    bf16x8 b3 = *(const bf16x8*)(Bb_ + 1536);                              \
    __builtin_amdgcn_s_setprio(1);                                         \
    acc[0][0] = MF16(a0, b0, acc[0][0]); acc[0][1] = MF16(a0, b1, acc[0][1]); \
    acc[0][2] = MF16(a0, b2, acc[0][2]); acc[0][3] = MF16(a0, b3, acc[0][3]); \
    acc[1][0] = MF16(a1, b0, acc[1][0]); acc[1][1] = MF16(a1, b1, acc[1][1]); \
    acc[1][2] = MF16(a1, b2, acc[1][2]); acc[1][3] = MF16(a1, b3, acc[1][3]); \
    acc[2][0] = MF16(a2, b0, acc[2][0]); acc[2][1] = MF16(a2, b1, acc[2][1]); \
    acc[2][2] = MF16(a2, b2, acc[2][2]); acc[2][3] = MF16(a2, b3, acc[2][3]); \
    acc[3][0] = MF16(a3, b0, acc[3][0]); acc[3][1] = MF16(a3, b1, acc[3][1]); \
    acc[3][2] = MF16(a3, b2, acc[3][2]); acc[3][3] = MF16(a3, b3, acc[3][3]); \
    __builtin_amdgcn_s_setprio(0);                                         \
    __builtin_amdgcn_sched_barrier(0);                                     \
    __builtin_amdgcn_s_barrier();                                          \
    __builtin_amdgcn_sched_barrier(0);                                     \
    STAGE_STMT;                                                            \
    WAIT_STMT;                                                             \
    __builtin_amdgcn_sched_barrier(0);                                     \
    __builtin_amdgcn_s_barrier();                                          \
    __builtin_amdgcn_sched_barrier(0);                                     \
  }

  const int NT = K >> 5;  // 32 for K=1024; even, >= 4

  STGP(0, 0);
  STGP(1, 32);
  VMW(3);
  __builtin_amdgcn_sched_barrier(0);
  __builtin_amdgcn_s_barrier();
  __builtin_amdgcn_sched_barrier(0);

  for (int i = 0; i < NT - 2; i += 2) {
    BODYP(0, STGP(0, (i + 2) * 32), VMW(3));
    BODYP(1, STGP(1, (i + 3) * 32), VMW(3));
  }
  BODYP(0, NOPS, VMW(0));
  BODYP(1, NOPS, NOPS);

  // epilogue: f32 partial, direct stores
  float* P = P0 + (long)z * czl;
#pragma unroll
  for (int ct = 0; ct < 4; ct++) {
    const int col = bn0 + wn * 64 + ct * 16 + llo;
#pragma unroll
    for (int rt = 0; rt < 4; rt++) {
#pragma unroll
      for (int r = 0; r < 4; r++) {
        const int row = bm0 + wm * 64 + rt * 16 + lhi * 4 + r;
        P[(long)row * ldc + col] = acc[rt][ct][r];
      }
    }
  }
#undef STGP
#undef BODYP
}

// ---------- launch ----------
extern "C" void kernel_launch(void* const* d_in, const int* in_sizes, int n_in,
                              void* d_out, int out_size, void* d_ws, size_t ws_size,
                              hipStream_t stream) {
  const float* x   = (const float*)d_in[0];
  // d_in[1] = mask (int32) — unused in infer path
  const float* g1  = (const float*)d_in[2];
  const float* b1  = (const float*)d_in[3];
  const float* Wq  = (const float*)d_in[4];
  const float* bq  = (const float*)d_in[5];
  const float* Wk  = (const float*)d_in[6];
  const float* bk  = (const float*)d_in[7];
  const float* Wv  = (const float*)d_in[8];
  const float* bv  = (const float*)d_in[9];
  const float* g2  = (const float*)d_in[10];
  const float* b2  = (const float*)d_in[11];
  const float* W1  = (const float*)d_in[12];
  const float* bw1 = (const float*)d_in[13];
  const float* W2  = (const float*)d_in[14];
  const float* bw2 = (const float*)d_in[15];

  char* ws = (char*)d_ws;
  const long MB = 1024 * 1024;
  // layout (peak 137MB; ws >= 189MB proven in round 5):
  float* bQKV  = (float*)(ws);            // [3][1024] f32: bq | bk | bv8
  float* x1    = (float*)(ws + 1 * MB);   // [4096,1024] f32  [1,17)
  short* wqT   = (short*)(ws + 17 * MB);  // [17,19)
  short* wkT   = (short*)(ws + 19 * MB);  // [19,21)  contiguous with wqT
  short* wv8T  = (short*)(ws + 21 * MB);  // [21,23)  contiguous (z*2MB)
  short* xn    = (short*)(ws + 23 * MB);  // [23,31)
  short* Q     = (short*)(ws + 31 * MB);  // [31,39)
  short* Kb    = (short*)(ws + 39 * MB);  // [39,47)  contiguous with Q
  short* V8T   = (short*)(ws + 47 * MB);  // [32][128][1024] bf16 [47,55)
  // FFN overlay (attention scratch dead by then):
  short* xn2  = (short*)(ws + 17 * MB);  // [17,25)
  short* Hb   = (short*)(ws + 25 * MB);  // [25,57)
  short* w1T  = (short*)(ws + 57 * MB);  // [57,65)
  short* w2T  = (short*)(ws + 65 * MB);  // [65,73)
  float* part = (float*)(ws + 73 * MB);  // [4][4096,1024] f32 [73,137)

  // fused prep: pair-pipelined transposes + wv8 + biases + LN1
  prep_k<<<5638, 256, 0, stream>>>(x, g1, b1, xn,
                                   Wq, wqT, Wk, wkT, Wv, wv8T,
                                   W1, w1T, W2, w2T,
                                   bq, bk, bv, bQKV);

  // QKV: z=0 -> Q (pre-scaled), z=1 -> Kb, z=2 -> V8T (transposed). K=1024.
  gemm256<E_QKV><<<dim3(4, 16, 3), 512, 0, stream>>>(
      xn, 1024, 0, wqT, 1024, 1048576, bQKV, 1024,
      Q, 4194304, 1024, V8T, 1024);

  // fused attention: scores+softmax+PV8+head-sum+residual -> x1
  flash_k<<<dim3(16, 32), 256, 0, stream>>>(Q, Kb, V8T, x, x1);

  // ---- FFN phase ----
  ln_k<<<4096, 256, 0, stream>>>(x1, g2, b2, xn2);

  // FFN1 + exact GELU -> Hb (bf16): 128x256 tiles, 2 blocks/CU. K=1024.
  gemm128n_gelu<<<dim3(16, 32), 512, 0, stream>>>(
      xn2, 1024, w1T, 1024, bw1, Hb, 4096, 1024);

  // FFN2 split-K=4: 128x256 tiles, 3 blocks/CU residency; f32 partials.
  gemm128n_part<<<dim3(4, 32, 4), 512, 0, stream>>>(
      Hb, 4096, 1024, w2T, 4096, 1024,
      part, 4194304, 1024, 1024);

  reduce4_k<<<4096, 256, 0, stream>>>(part, x1, bw2, (float*)d_out);
}